// Round 4
// baseline (1068.245 us; speedup 1.0000x reference)
//
#include <hip/hip_runtime.h>
#include <math.h>

constexpr float DELTA_ = 2.5f;
#define BN_BLOCKS 512

// ---------- small prep kernels ----------

__global__ __launch_bounds__(256) void k_tU(const float* __restrict__ Uw, float* __restrict__ UwT){
  int i = blockIdx.x*256 + threadIdx.x;            // i = (t*832 + k)*64 + o
  if (i >= 4*832*64) return;
  int o = i & 63;
  int k = (i >> 6) % 832;
  int t = (i >> 6) / 832;
  UwT[i] = Uw[(size_t)(t*64 + o)*832 + k];
}

__global__ __launch_bounds__(256) void k_tM(const float* __restrict__ Mx, float* __restrict__ MxT){
  int i = blockIdx.x*256 + threadIdx.x;            // i = k*256 + j
  if (i >= 256*256) return;
  int j = i & 255, k = i >> 8;
  MxT[i] = Mx[j*256 + k];
}

__global__ __launch_bounds__(256) void k_hist(const int* __restrict__ dstv, int* __restrict__ cnt, int E){
  int e = blockIdx.x*256 + threadIdx.x;
  if (e < E) atomicAdd(&cnt[dstv[e]], 1);
}

__global__ __launch_bounds__(256) void k_scan1(const int* __restrict__ cnt, int* __restrict__ offs,
                                               int* __restrict__ bsum, int N){
  __shared__ int lds[256];
  int i = threadIdx.x;
  int g = blockIdx.x*256 + i;
  int v = (g < N) ? cnt[g] : 0;
  int acc = v;
  lds[i] = acc; __syncthreads();
  for (int s = 1; s < 256; s <<= 1){
    int t = (i >= s) ? lds[i - s] : 0;
    __syncthreads();
    acc += t; lds[i] = acc;
    __syncthreads();
  }
  if (g < N) offs[g] = acc - v;                    // exclusive within block
  if (i == 255) bsum[blockIdx.x] = acc;
}

__global__ __launch_bounds__(256) void k_scan2(int* __restrict__ bsum, int NB){
  __shared__ int lds[256];
  int i = threadIdx.x;
  int v = (i < NB) ? bsum[i] : 0;
  int acc = v;
  lds[i] = acc; __syncthreads();
  for (int s = 1; s < 256; s <<= 1){
    int t = (i >= s) ? lds[i - s] : 0;
    __syncthreads();
    acc += t; lds[i] = acc;
    __syncthreads();
  }
  if (i < NB) bsum[i] = acc - v;                   // exclusive block offsets
}

__global__ __launch_bounds__(256) void k_scan3(int* __restrict__ offs, const int* __restrict__ bsum, int N, int E){
  int g = blockIdx.x*256 + threadIdx.x;
  if (g < N) offs[g] += bsum[blockIdx.x];
  if (g == 0) offs[N] = E;
}

__global__ __launch_bounds__(256) void k_fill(const int* __restrict__ dstv, const int* __restrict__ offs,
                                              int* __restrict__ cur, int* __restrict__ elist, int E){
  int e = blockIdx.x*256 + threadIdx.x;
  if (e < E){
    int d = dstv[e];
    elist[offs[d] + atomicAdd(&cur[d], 1)] = e;
  }
}

// ---------- permute srcv + edge features into CSR order (kills dependent chain) ----------

__global__ __launch_bounds__(256) void k_perm(const int* __restrict__ elist, const int* __restrict__ srcv,
                                              const float* __restrict__ efeat,
                                              int* __restrict__ esrc, float* __restrict__ efp, int E){
  int g = blockIdx.x*256 + threadIdx.x;
  int pos = g >> 3;                                // 8 threads per edge
  int q   = g & 7;
  if (pos >= E) return;
  int e = elist[pos];
  if (q == 0) esrc[pos] = srcv[e];
  float4 v = *(const float4*)(efeat + (size_t)e*32 + q*4);
  *(float4*)(efp + (size_t)pos*32 + q*4) = v;      // coalesced write
}

// ---------- A = W_src*h, B = W_dst*h + M_b (per node) ----------

__global__ __launch_bounds__(256) void k_ab(const float* __restrict__ nf, const float* __restrict__ Mw,
                                            const float* __restrict__ Mb,
                                            float* __restrict__ A, float* __restrict__ B, int N){
  int c = threadIdx.x;
  int t = __builtin_amdgcn_readfirstlane(threadIdx.x >> 6);
  float ws[64], wd[64];
  const float* row = Mw + (size_t)c*160;
#pragma unroll
  for (int k = 0; k < 64; k += 4){
    float4 a = *(const float4*)(row + k);
    float4 b = *(const float4*)(row + 64 + k);
    ws[k]=a.x; ws[k+1]=a.y; ws[k+2]=a.z; ws[k+3]=a.w;
    wd[k]=b.x; wd[k+1]=b.y; wd[k+2]=b.z; wd[k+3]=b.w;
  }
  float bias = Mb[c];
  for (int n = blockIdx.x; n < N; n += gridDim.x){
    const float* h = nf + (size_t)n*256 + t*64;
    float sa = 0.f, sb = 0.f;
#pragma unroll
    for (int k = 0; k < 64; k += 4){
      float4 h4 = *(const float4*)(h + k);
      sa = fmaf(ws[k], h4.x, sa);  sb = fmaf(wd[k], h4.x, sb);
      sa = fmaf(ws[k+1], h4.y, sa); sb = fmaf(wd[k+1], h4.y, sb);
      sa = fmaf(ws[k+2], h4.z, sa); sb = fmaf(wd[k+2], h4.z, sb);
      sa = fmaf(ws[k+3], h4.w, sa); sb = fmaf(wd[k+3], h4.w, sb);
    }
    A[(size_t)n*256 + c] = sa;
    B[(size_t)n*256 + c] = sb + bias;
  }
}

// ---------- per-node aggregation: block = node, thread = channel ----------

__global__ __launch_bounds__(256) void k_agg(const int* __restrict__ offs, const int* __restrict__ esrc,
                                             const float* __restrict__ efp,
                                             const float* __restrict__ A, const float* __restrict__ B,
                                             const float* __restrict__ Mw,
                                             float* __restrict__ agg, float* __restrict__ sc, int N){
  int c = threadIdx.x;
  float4 wef[8];
  const float* wrow = Mw + (size_t)c*160 + 128;
#pragma unroll
  for (int q = 0; q < 8; ++q) wef[q] = *(const float4*)(wrow + 4*q);

  int n = blockIdx.x;
  if (n >= N) return;
  int o0 = __builtin_amdgcn_readfirstlane(offs[n]);
  int o1 = __builtin_amdgcn_readfirstlane(offs[n+1]);
  int cnt = o1 - o0;
  float b0 = B[(size_t)n*256 + c];
  float s = 0.f, ss = 0.f, mx = -__builtin_huge_valf(), mn = __builtin_huge_valf();

  int i = 0;
  for (; i + 4 <= cnt; i += 4){
    int p = o0 + i;
    int s0 = __builtin_amdgcn_readfirstlane(esrc[p+0]);
    int s1 = __builtin_amdgcn_readfirstlane(esrc[p+1]);
    int s2 = __builtin_amdgcn_readfirstlane(esrc[p+2]);
    int s3 = __builtin_amdgcn_readfirstlane(esrc[p+3]);
    const float* f0 = efp + (size_t)(p+0)*32;
    const float* f1 = efp + (size_t)(p+1)*32;
    const float* f2 = efp + (size_t)(p+2)*32;
    const float* f3 = efp + (size_t)(p+3)*32;
    float a0 = A[(size_t)s0*256 + c];
    float a1 = A[(size_t)s1*256 + c];
    float a2 = A[(size_t)s2*256 + c];
    float a3 = A[(size_t)s3*256 + c];
    float m0 = b0 + a0;
    float m1 = b0 + a1;
    float m2 = b0 + a2;
    float m3 = b0 + a3;
#pragma unroll
    for (int q = 0; q < 8; ++q){
      float4 e0 = *(const float4*)(f0 + 4*q);
      float4 e1 = *(const float4*)(f1 + 4*q);
      float4 e2 = *(const float4*)(f2 + 4*q);
      float4 e3 = *(const float4*)(f3 + 4*q);
      m0 = fmaf(e0.x, wef[q].x, m0); m0 = fmaf(e0.y, wef[q].y, m0);
      m0 = fmaf(e0.z, wef[q].z, m0); m0 = fmaf(e0.w, wef[q].w, m0);
      m1 = fmaf(e1.x, wef[q].x, m1); m1 = fmaf(e1.y, wef[q].y, m1);
      m1 = fmaf(e1.z, wef[q].z, m1); m1 = fmaf(e1.w, wef[q].w, m1);
      m2 = fmaf(e2.x, wef[q].x, m2); m2 = fmaf(e2.y, wef[q].y, m2);
      m2 = fmaf(e2.z, wef[q].z, m2); m2 = fmaf(e2.w, wef[q].w, m2);
      m3 = fmaf(e3.x, wef[q].x, m3); m3 = fmaf(e3.y, wef[q].y, m3);
      m3 = fmaf(e3.z, wef[q].z, m3); m3 = fmaf(e3.w, wef[q].w, m3);
    }
    s += m0; s += m1; s += m2; s += m3;
    ss = fmaf(m0, m0, ss); ss = fmaf(m1, m1, ss);
    ss = fmaf(m2, m2, ss); ss = fmaf(m3, m3, ss);
    mx = fmaxf(mx, fmaxf(fmaxf(m0, m1), fmaxf(m2, m3)));
    mn = fminf(mn, fminf(fminf(m0, m1), fminf(m2, m3)));
  }
  for (; i < cnt; ++i){
    int p = o0 + i;
    int sidx = __builtin_amdgcn_readfirstlane(esrc[p]);
    const float* ef = efp + (size_t)p*32;
    float m = b0 + A[(size_t)sidx*256 + c];
#pragma unroll
    for (int q = 0; q < 8; ++q){
      float4 e4 = *(const float4*)(ef + 4*q);
      m = fmaf(e4.x, wef[q].x, m);
      m = fmaf(e4.y, wef[q].y, m);
      m = fmaf(e4.z, wef[q].z, m);
      m = fmaf(e4.w, wef[q].w, m);
    }
    s += m;
    ss = fmaf(m, m, ss);
    mx = fmaxf(mx, m);
    mn = fminf(mn, m);
  }

  float deg  = (float)cnt;
  float degc = fmaxf(deg, 1.f);
  float inv  = 1.f / degc;
  float mean = s * inv;
  float var  = fmaxf(ss * inv - mean*mean, 0.f);
  float sd   = sqrtf(var + 1e-30f);
  if (cnt == 0){ mx = 0.f; mn = 0.f; }
  float* ar = agg + (size_t)n*1024 + (size_t)(c >> 6)*256 + (c & 63);
  ar[0]   = mean;
  ar[64]  = mx;
  ar[128] = mn;
  ar[192] = sd;
  if (c == 0){
    float logd = logf(deg + 1.f);
    sc[(size_t)n*2]     = logd * (1.f / DELTA_);
    sc[(size_t)n*2 + 1] = (cnt > 0) ? (DELTA_ / fmaxf(logd, 1e-12f)) : 0.f;
  }
}

// ---------- U GEMM: lane = node, 8 waves = (tower, out-half), thread owns 32 out ----------
// Activation loads software-pipelined 1-deep: always >=1 outstanding global load
// per wave during the FMA block (we run at only ~2 waves/SIMD, so intra-wave ILP
// is the latency hiding).

#define ROW_FMA32(WPTR, AV) { const float* __wr = (WPTR); \
  _Pragma("unroll") for (int c2 = 0; c2 < 32; ++c2) acc[c2] = fmaf(__wr[c2], (AV), acc[c2]); }

__global__ __launch_bounds__(512) void k_u(const float* __restrict__ nf, const float* __restrict__ agg,
                                           const float* __restrict__ sc, const float* __restrict__ UwT,
                                           const float* __restrict__ Ub, float* __restrict__ uout, int N){
  int lane = threadIdx.x & 63;
  int wv   = threadIdx.x >> 6;                       // 0..7
  int t  = __builtin_amdgcn_readfirstlane(wv >> 1);  // tower
  int hf = __builtin_amdgcn_readfirstlane(wv & 1);   // out-channel half
  int n = blockIdx.x*64 + lane;
  bool valid = (n < N);
  if (!valid) n = N - 1;
  float amp = sc[(size_t)n*2];
  float att = sc[(size_t)n*2 + 1];
  const float* wt = UwT + (size_t)t*832*64 + hf*32;
  float acc[32];
#pragma unroll
  for (int c2 = 0; c2 < 32; ++c2) acc[c2] = 0.f;

  const float* h  = nf  + (size_t)n*256  + t*64;
  const float* ag = agg + (size_t)n*1024 + t*256;

  // h part: k in [0,64), prefetched 1-deep
  float4 c4 = *(const float4*)(h);
#pragma unroll 2
  for (int q = 0; q < 16; ++q){
    float4 n4 = (q < 15) ? *(const float4*)(h + 4*(q+1)) : *(const float4*)(ag);
    const float* w0 = wt + (size_t)(4*q)*64;
    ROW_FMA32(w0,        c4.x);
    ROW_FMA32(w0 + 64,   c4.y);
    ROW_FMA32(w0 + 128,  c4.z);
    ROW_FMA32(w0 + 192,  c4.w);
    c4 = n4;
  }
  // agg / agg*amp / agg*att parts: k in [64,832); c4 holds ag[0..3]
#pragma unroll 2
  for (int q = 0; q < 64; ++q){
    float4 n4 = (q < 63) ? *(const float4*)(ag + 4*(q+1)) : make_float4(0.f,0.f,0.f,0.f);
    float ax = c4.x*amp, ay = c4.y*amp, az = c4.z*amp, aw = c4.w*amp;
    float tx = c4.x*att, ty = c4.y*att, tz = c4.z*att, tw = c4.w*att;
    const float* wA  = wt + (size_t)(64  + 4*q)*64;
    const float* wAA = wt + (size_t)(320 + 4*q)*64;
    const float* wAT = wt + (size_t)(576 + 4*q)*64;
    ROW_FMA32(wA,         c4.x); ROW_FMA32(wA + 64,   c4.y);
    ROW_FMA32(wA + 128,   c4.z); ROW_FMA32(wA + 192,  c4.w);
    ROW_FMA32(wAA,        ax);   ROW_FMA32(wAA + 64,  ay);
    ROW_FMA32(wAA + 128,  az);   ROW_FMA32(wAA + 192, aw);
    ROW_FMA32(wAT,        tx);   ROW_FMA32(wAT + 64,  ty);
    ROW_FMA32(wAT + 128,  tz);   ROW_FMA32(wAT + 192, tw);
    c4 = n4;
  }
  if (valid){
    float* up = uout + (size_t)n*256 + t*64 + hf*32;
    const float* ub = Ub + t*64 + hf*32;
#pragma unroll
    for (int c2 = 0; c2 < 32; c2 += 4){
      float4 v;
      v.x = acc[c2]   + ub[c2];
      v.y = acc[c2+1] + ub[c2+1];
      v.z = acc[c2+2] + ub[c2+2];
      v.w = acc[c2+3] + ub[c2+3];
      *(float4*)(up + c2) = v;
    }
  }
}

// ---------- batchnorm stats (deterministic: fixed partials, no float atomics) ----------

__global__ __launch_bounds__(256) void k_bnstat(const float* __restrict__ u, float* __restrict__ part, int N){
  int c = threadIdx.x;
  int b = blockIdx.x;
  float s = 0.f, ss = 0.f;
  for (int n = b; n < N; n += gridDim.x){
    float v = u[(size_t)n*256 + c];
    s += v;
    ss = fmaf(v, v, ss);
  }
  part[(size_t)b*512 + c]       = s;
  part[(size_t)b*512 + 256 + c] = ss;
}

__global__ __launch_bounds__(256) void k_bnfin(const float* __restrict__ part, const float* __restrict__ gam,
                                               const float* __restrict__ bet, float* __restrict__ bnsc, int N){
  int c = threadIdx.x;
  float s = 0.f, ss = 0.f;
  for (int b = 0; b < BN_BLOCKS; ++b){
    s  += part[(size_t)b*512 + c];
    ss += part[(size_t)b*512 + 256 + c];
  }
  float invN = 1.f / (float)N;
  float mu  = s * invN;
  float ex2 = ss * invN;
  float var = fmaxf(ex2 - mu*mu, 0.f);
  float inv = 1.f / sqrtf(var + 1e-5f);
  float scale = gam[c] * inv;
  bnsc[c]       = scale;
  bnsc[256 + c] = bet[c] - mu*scale;
}

// ---------- mix GEMM + leaky + residual + relu (in-place on uo) ----------

#define ROW_FMA(WPTR, AV) { const float* __wr = (WPTR); \
  _Pragma("unroll") for (int c2 = 0; c2 < 64; ++c2) acc[c2] = fmaf(__wr[c2], (AV), acc[c2]); }

__global__ __launch_bounds__(256) void k_mix(float* uo, const float* __restrict__ bnsc,
                                             const float* __restrict__ mixT, const float* __restrict__ mixb,
                                             const float* __restrict__ nf, int N){
  int lane = threadIdx.x & 63;
  int w = __builtin_amdgcn_readfirstlane(threadIdx.x >> 6);
  int n = blockIdx.x*64 + lane;
  bool valid = (n < N);
  if (!valid) n = N - 1;
  float acc[64];
#pragma unroll
  for (int c2 = 0; c2 < 64; ++c2) acc[c2] = 0.f;
  const float* ur = uo + (size_t)n*256;
  float4 u4 = *(const float4*)(ur);
#pragma unroll 2
  for (int q = 0; q < 64; ++q){
    float4 un = (q < 63) ? *(const float4*)(ur + 4*(q+1)) : make_float4(0.f,0.f,0.f,0.f);
    float4 s4 = *(const float4*)(bnsc + 4*q);
    float4 h4 = *(const float4*)(bnsc + 256 + 4*q);
    float a0 = fmaf(u4.x, s4.x, h4.x);
    float a1 = fmaf(u4.y, s4.y, h4.y);
    float a2 = fmaf(u4.z, s4.z, h4.z);
    float a3 = fmaf(u4.w, s4.w, h4.w);
    const float* w0 = mixT + (size_t)(4*q)*256 + w*64;
    ROW_FMA(w0,       a0);
    ROW_FMA(w0 + 256, a1);
    ROW_FMA(w0 + 512, a2);
    ROW_FMA(w0 + 768, a3);
    u4 = un;
  }
  __syncthreads();   // all waves done READING u rows before any wave overwrites them
  if (valid){
    int j0 = w*64;
    const float* r = nf + (size_t)n*256 + j0;
    float* op = uo + (size_t)n*256 + j0;
#pragma unroll
    for (int c2 = 0; c2 < 64; c2 += 4){
      float4 v;
      float m0 = acc[c2]   + mixb[j0 + c2];
      float m1 = acc[c2+1] + mixb[j0 + c2 + 1];
      float m2 = acc[c2+2] + mixb[j0 + c2 + 2];
      float m3 = acc[c2+3] + mixb[j0 + c2 + 3];
      m0 = (m0 > 0.f) ? m0 : 0.01f*m0;
      m1 = (m1 > 0.f) ? m1 : 0.01f*m1;
      m2 = (m2 > 0.f) ? m2 : 0.01f*m2;
      m3 = (m3 > 0.f) ? m3 : 0.01f*m3;
      v.x = fmaxf(m0 + r[c2],   0.f);
      v.y = fmaxf(m1 + r[c2+1], 0.f);
      v.z = fmaxf(m2 + r[c2+2], 0.f);
      v.w = fmaxf(m3 + r[c2+3], 0.f);
      *(float4*)(op + c2) = v;
    }
  }
}

// ---------- host launcher ----------

extern "C" void kernel_launch(void* const* d_in, const int* in_sizes, int n_in,
                              void* d_out, int out_size, void* d_ws, size_t ws_size,
                              hipStream_t stream){
  const float* nf   = (const float*)d_in[0];
  const float* ef   = (const float*)d_in[1];
  const int*   srcv = (const int*)  d_in[2];
  const int*   dstv = (const int*)  d_in[3];
  const float* Mw   = (const float*)d_in[4];
  const float* Mb   = (const float*)d_in[5];
  const float* Uw   = (const float*)d_in[6];
  const float* Ub   = (const float*)d_in[7];
  const float* gam  = (const float*)d_in[8];
  const float* bet  = (const float*)d_in[9];
  const float* mixw = (const float*)d_in[10];
  const float* mixb = (const float*)d_in[11];
  int N = in_sizes[0] / 256;
  int E = in_sizes[2];
  float* out = (float*)d_out;

  char* wp = (char*)d_ws;
  auto alloc = [&](size_t bytes){
    char* p = wp;
    wp += (bytes + 1023) & ~(size_t)1023;
    return (void*)p;
  };
  int*   cnt   = (int*)  alloc((size_t)N*4);
  int*   offs  = (int*)  alloc((size_t)(N+1)*4);
  int*   cur   = (int*)  alloc((size_t)N*4);
  int*   bsum  = (int*)  alloc(256*4);
  int*   elist = (int*)  alloc((size_t)E*4);
  int*   esrc  = (int*)  alloc((size_t)E*4);
  float* efp   = (float*)alloc((size_t)E*32*4);
  float* A     = (float*)alloc((size_t)N*256*4);
  float* B     = (float*)alloc((size_t)N*256*4);
  float* agg   = (float*)alloc((size_t)N*1024*4);
  float* sc    = (float*)alloc((size_t)N*2*4);
  float* part  = (float*)alloc((size_t)BN_BLOCKS*512*4);
  float* bnsc  = (float*)alloc(512*4);
  float* UwT   = (float*)alloc((size_t)4*832*64*4);
  float* mixT  = (float*)alloc((size_t)256*256*4);

  hipMemsetAsync(cnt,  0, (size_t)N*4,  stream);
  hipMemsetAsync(cur,  0, (size_t)N*4,  stream);

  k_tU  <<<(4*832*64 + 255)/256, 256, 0, stream>>>(Uw, UwT);
  k_tM  <<<256, 256, 0, stream>>>(mixw, mixT);
  k_hist<<<(E + 255)/256, 256, 0, stream>>>(dstv, cnt, E);
  k_ab  <<<2048, 256, 0, stream>>>(nf, Mw, Mb, A, B, N);

  int NB = (N + 255)/256;
  k_scan1<<<NB, 256, 0, stream>>>(cnt, offs, bsum, N);
  k_scan2<<<1, 256, 0, stream>>>(bsum, NB);
  k_scan3<<<NB, 256, 0, stream>>>(offs, bsum, N, E);
  k_fill <<<(E + 255)/256, 256, 0, stream>>>(dstv, offs, cur, elist, E);
  k_perm <<<(E*8 + 255)/256, 256, 0, stream>>>(elist, srcv, ef, esrc, efp, E);

  k_agg<<<N, 256, 0, stream>>>(offs, esrc, efp, A, B, Mw, agg, sc, N);
  k_u  <<<(N + 63)/64, 512, 0, stream>>>(nf, agg, sc, UwT, Ub, out, N);
  k_bnstat<<<BN_BLOCKS, 256, 0, stream>>>(out, part, N);
  k_bnfin <<<1, 256, 0, stream>>>(part, gam, bet, bnsc, N);
  k_mix<<<(N + 63)/64, 256, 0, stream>>>(out, bnsc, mixT, mixb, nf, N);
}

// Round 5
// 754.319 us; speedup vs baseline: 1.4162x; 1.4162x over previous
//
#include <hip/hip_runtime.h>
#include <math.h>

constexpr float DELTA_ = 2.5f;
#define BN_BLOCKS 512

// ---------- small prep kernels ----------

// UwT2[kk][o] = Uw[o>>6][o&63][kk]  -> [832][256], rows contiguous over o
__global__ __launch_bounds__(256) void k_tU(const float* __restrict__ Uw, float* __restrict__ UwT2){
  int i = blockIdx.x*256 + threadIdx.x;            // i = kk*256 + o
  if (i >= 832*256) return;
  int o  = i & 255;
  int kk = i >> 8;
  UwT2[i] = Uw[((size_t)(o >> 6)*64 + (o & 63))*832 + kk];
}

__global__ __launch_bounds__(256) void k_tM(const float* __restrict__ Mx, float* __restrict__ MxT){
  int i = blockIdx.x*256 + threadIdx.x;            // i = k*256 + j
  if (i >= 256*256) return;
  int j = i & 255, k = i >> 8;
  MxT[i] = Mx[j*256 + k];
}

__global__ __launch_bounds__(256) void k_hist(const int* __restrict__ dstv, int* __restrict__ cnt, int E){
  int e = blockIdx.x*256 + threadIdx.x;
  if (e < E) atomicAdd(&cnt[dstv[e]], 1);
}

__global__ __launch_bounds__(256) void k_scan1(const int* __restrict__ cnt, int* __restrict__ offs,
                                               int* __restrict__ bsum, int N){
  __shared__ int lds[256];
  int i = threadIdx.x;
  int g = blockIdx.x*256 + i;
  int v = (g < N) ? cnt[g] : 0;
  int acc = v;
  lds[i] = acc; __syncthreads();
  for (int s = 1; s < 256; s <<= 1){
    int t = (i >= s) ? lds[i - s] : 0;
    __syncthreads();
    acc += t; lds[i] = acc;
    __syncthreads();
  }
  if (g < N) offs[g] = acc - v;                    // exclusive within block
  if (i == 255) bsum[blockIdx.x] = acc;
}

__global__ __launch_bounds__(256) void k_scan2(int* __restrict__ bsum, int NB){
  __shared__ int lds[256];
  int i = threadIdx.x;
  int v = (i < NB) ? bsum[i] : 0;
  int acc = v;
  lds[i] = acc; __syncthreads();
  for (int s = 1; s < 256; s <<= 1){
    int t = (i >= s) ? lds[i - s] : 0;
    __syncthreads();
    acc += t; lds[i] = acc;
    __syncthreads();
  }
  if (i < NB) bsum[i] = acc - v;                   // exclusive block offsets
}

__global__ __launch_bounds__(256) void k_scan3(int* __restrict__ offs, const int* __restrict__ bsum, int N, int E){
  int g = blockIdx.x*256 + threadIdx.x;
  if (g < N) offs[g] += bsum[blockIdx.x];
  if (g == 0) offs[N] = E;
}

__global__ __launch_bounds__(256) void k_fill(const int* __restrict__ dstv, const int* __restrict__ offs,
                                              int* __restrict__ cur, int* __restrict__ elist, int E){
  int e = blockIdx.x*256 + threadIdx.x;
  if (e < E){
    int d = dstv[e];
    elist[offs[d] + atomicAdd(&cur[d], 1)] = e;
  }
}

// ---------- permute srcv + edge features into CSR order ----------

__global__ __launch_bounds__(256) void k_perm(const int* __restrict__ elist, const int* __restrict__ srcv,
                                              const float* __restrict__ efeat,
                                              int* __restrict__ esrc, float* __restrict__ efp, int E){
  int g = blockIdx.x*256 + threadIdx.x;
  int pos = g >> 3;                                // 8 threads per edge
  int q   = g & 7;
  if (pos >= E) return;
  int e = elist[pos];
  if (q == 0) esrc[pos] = srcv[e];
  float4 v = *(const float4*)(efeat + (size_t)e*32 + q*4);
  *(float4*)(efp + (size_t)pos*32 + q*4) = v;      // coalesced write
}

// ---------- A = W_src*h, B = W_dst*h + M_b (per node) ----------

__global__ __launch_bounds__(256) void k_ab(const float* __restrict__ nf, const float* __restrict__ Mw,
                                            const float* __restrict__ Mb,
                                            float* __restrict__ A, float* __restrict__ B, int N){
  int c = threadIdx.x;
  int t = __builtin_amdgcn_readfirstlane(threadIdx.x >> 6);
  float ws[64], wd[64];
  const float* row = Mw + (size_t)c*160;
#pragma unroll
  for (int k = 0; k < 64; k += 4){
    float4 a = *(const float4*)(row + k);
    float4 b = *(const float4*)(row + 64 + k);
    ws[k]=a.x; ws[k+1]=a.y; ws[k+2]=a.z; ws[k+3]=a.w;
    wd[k]=b.x; wd[k+1]=b.y; wd[k+2]=b.z; wd[k+3]=b.w;
  }
  float bias = Mb[c];
  for (int n = blockIdx.x; n < N; n += gridDim.x){
    const float* h = nf + (size_t)n*256 + t*64;
    float sa = 0.f, sb = 0.f;
#pragma unroll
    for (int k = 0; k < 64; k += 4){
      float4 h4 = *(const float4*)(h + k);
      sa = fmaf(ws[k], h4.x, sa);  sb = fmaf(wd[k], h4.x, sb);
      sa = fmaf(ws[k+1], h4.y, sa); sb = fmaf(wd[k+1], h4.y, sb);
      sa = fmaf(ws[k+2], h4.z, sa); sb = fmaf(wd[k+2], h4.z, sb);
      sa = fmaf(ws[k+3], h4.w, sa); sb = fmaf(wd[k+3], h4.w, sb);
    }
    A[(size_t)n*256 + c] = sa;
    B[(size_t)n*256 + c] = sb + bias;
  }
}

// ---------- per-node aggregation: block = node, thread = channel ----------

__global__ __launch_bounds__(256) void k_agg(const int* __restrict__ offs, const int* __restrict__ esrc,
                                             const float* __restrict__ efp,
                                             const float* __restrict__ A, const float* __restrict__ B,
                                             const float* __restrict__ Mw,
                                             float* __restrict__ agg, float* __restrict__ sc, int N){
  int c = threadIdx.x;
  float4 wef[8];
  const float* wrow = Mw + (size_t)c*160 + 128;
#pragma unroll
  for (int q = 0; q < 8; ++q) wef[q] = *(const float4*)(wrow + 4*q);

  int n = blockIdx.x;
  if (n >= N) return;
  int o0 = __builtin_amdgcn_readfirstlane(offs[n]);
  int o1 = __builtin_amdgcn_readfirstlane(offs[n+1]);
  int cnt = o1 - o0;
  float b0 = B[(size_t)n*256 + c];
  float s = 0.f, ss = 0.f, mx = -__builtin_huge_valf(), mn = __builtin_huge_valf();

  int i = 0;
  for (; i + 4 <= cnt; i += 4){
    int p = o0 + i;
    int s0 = __builtin_amdgcn_readfirstlane(esrc[p+0]);
    int s1 = __builtin_amdgcn_readfirstlane(esrc[p+1]);
    int s2 = __builtin_amdgcn_readfirstlane(esrc[p+2]);
    int s3 = __builtin_amdgcn_readfirstlane(esrc[p+3]);
    const float* f0 = efp + (size_t)(p+0)*32;
    const float* f1 = efp + (size_t)(p+1)*32;
    const float* f2 = efp + (size_t)(p+2)*32;
    const float* f3 = efp + (size_t)(p+3)*32;
    float a0 = A[(size_t)s0*256 + c];
    float a1 = A[(size_t)s1*256 + c];
    float a2 = A[(size_t)s2*256 + c];
    float a3 = A[(size_t)s3*256 + c];
    float m0 = b0 + a0;
    float m1 = b0 + a1;
    float m2 = b0 + a2;
    float m3 = b0 + a3;
#pragma unroll
    for (int q = 0; q < 8; ++q){
      float4 e0 = *(const float4*)(f0 + 4*q);
      float4 e1 = *(const float4*)(f1 + 4*q);
      float4 e2 = *(const float4*)(f2 + 4*q);
      float4 e3 = *(const float4*)(f3 + 4*q);
      m0 = fmaf(e0.x, wef[q].x, m0); m0 = fmaf(e0.y, wef[q].y, m0);
      m0 = fmaf(e0.z, wef[q].z, m0); m0 = fmaf(e0.w, wef[q].w, m0);
      m1 = fmaf(e1.x, wef[q].x, m1); m1 = fmaf(e1.y, wef[q].y, m1);
      m1 = fmaf(e1.z, wef[q].z, m1); m1 = fmaf(e1.w, wef[q].w, m1);
      m2 = fmaf(e2.x, wef[q].x, m2); m2 = fmaf(e2.y, wef[q].y, m2);
      m2 = fmaf(e2.z, wef[q].z, m2); m2 = fmaf(e2.w, wef[q].w, m2);
      m3 = fmaf(e3.x, wef[q].x, m3); m3 = fmaf(e3.y, wef[q].y, m3);
      m3 = fmaf(e3.z, wef[q].z, m3); m3 = fmaf(e3.w, wef[q].w, m3);
    }
    s += m0; s += m1; s += m2; s += m3;
    ss = fmaf(m0, m0, ss); ss = fmaf(m1, m1, ss);
    ss = fmaf(m2, m2, ss); ss = fmaf(m3, m3, ss);
    mx = fmaxf(mx, fmaxf(fmaxf(m0, m1), fmaxf(m2, m3)));
    mn = fminf(mn, fminf(fminf(m0, m1), fminf(m2, m3)));
  }
  for (; i < cnt; ++i){
    int p = o0 + i;
    int sidx = __builtin_amdgcn_readfirstlane(esrc[p]);
    const float* ef = efp + (size_t)p*32;
    float m = b0 + A[(size_t)sidx*256 + c];
#pragma unroll
    for (int q = 0; q < 8; ++q){
      float4 e4 = *(const float4*)(ef + 4*q);
      m = fmaf(e4.x, wef[q].x, m);
      m = fmaf(e4.y, wef[q].y, m);
      m = fmaf(e4.z, wef[q].z, m);
      m = fmaf(e4.w, wef[q].w, m);
    }
    s += m;
    ss = fmaf(m, m, ss);
    mx = fmaxf(mx, m);
    mn = fminf(mn, m);
  }

  float deg  = (float)cnt;
  float degc = fmaxf(deg, 1.f);
  float inv  = 1.f / degc;
  float mean = s * inv;
  float var  = fmaxf(ss * inv - mean*mean, 0.f);
  float sd   = sqrtf(var + 1e-30f);
  if (cnt == 0){ mx = 0.f; mn = 0.f; }
  float* ar = agg + (size_t)n*1024 + (size_t)(c >> 6)*256 + (c & 63);
  ar[0]   = mean;
  ar[64]  = mx;
  ar[128] = mn;
  ar[192] = sd;
  if (c == 0){
    float logd = logf(deg + 1.f);
    sc[(size_t)n*2]     = logd * (1.f / DELTA_);
    sc[(size_t)n*2 + 1] = (cnt > 0) ? (DELTA_ / fmaxf(logd, 1e-12f)) : 0.f;
  }
}

// ---------- U GEMM: LDS-tiled fp32 GEMM ----------
// Per tower t (blockIdx.y): C[128 nodes x 64 outs] += X_t[128 x 832] * W_t[832 x 64].
// X_t segments (h / agg / agg*amp / agg*att) are built during staging by row-scaling.
// 128 threads, thread-tile 8 nodes x 8 outs, K-step 32.

__global__ __launch_bounds__(128) void k_u(const float* __restrict__ nf, const float* __restrict__ agg,
                                           const float* __restrict__ sc, const float* __restrict__ UwT2,
                                           const float* __restrict__ Ub, float* __restrict__ uout, int N){
  __shared__ float act_s[32][128];
  __shared__ float w_s[32][64];

  int tid = threadIdx.x;
  int t   = blockIdx.y;                      // tower (wave-uniform)
  int blk = blockIdx.x;                      // node tile

  // staging row = tid
  int nr = blk*128 + tid;
  int nrc = (nr < N) ? nr : (N - 1);
  float amp_r = sc[(size_t)nrc*2];
  float att_r = sc[(size_t)nrc*2 + 1];
  const float* h_row = nf  + (size_t)nrc*256  + t*64;
  const float* a_row = agg + (size_t)nrc*1024 + t*256;

  // compute sub-tile
  int nb = (tid & 15)*8;                     // node offset in tile
  int ob = (tid >> 4)*8;                     // out offset

  float acc[8][8];
#pragma unroll
  for (int i = 0; i < 8; ++i)
#pragma unroll
    for (int j = 0; j < 8; ++j) acc[i][j] = 0.f;

  for (int kt = 0; kt < 26; ++kt){
    // ---- stage ----
    const float* srcp; float scl;
    if (kt < 2)      { srcp = h_row + kt*32;        scl = 1.f;   }
    else if (kt < 10){ srcp = a_row + (kt-2)*32;    scl = 1.f;   }
    else if (kt < 18){ srcp = a_row + (kt-10)*32;   scl = amp_r; }
    else             { srcp = a_row + (kt-18)*32;   scl = att_r; }

    __syncthreads();                          // prior compute done reading LDS
#pragma unroll
    for (int q = 0; q < 8; ++q){
      float4 v = *(const float4*)(srcp + 4*q);
      act_s[4*q+0][tid] = v.x*scl;
      act_s[4*q+1][tid] = v.y*scl;
      act_s[4*q+2][tid] = v.z*scl;
      act_s[4*q+3][tid] = v.w*scl;
    }
#pragma unroll
    for (int j = 0; j < 4; ++j){
      int idx = tid + j*128;                  // 0..511 -> (k, o4)
      int kr  = idx >> 4;
      int o4  = (idx & 15)*4;
      float4 wv = *(const float4*)(UwT2 + (size_t)(kt*32 + kr)*256 + t*64 + o4);
      *(float4*)(&w_s[kr][o4]) = wv;
    }
    __syncthreads();

    // ---- compute 32 k ----
#pragma unroll 2
    for (int k = 0; k < 32; ++k){
      float4 a0 = *(const float4*)(&act_s[k][nb]);
      float4 a1 = *(const float4*)(&act_s[k][nb+4]);
      float4 w0 = *(const float4*)(&w_s[k][ob]);
      float4 w1 = *(const float4*)(&w_s[k][ob+4]);
      float av[8] = {a0.x,a0.y,a0.z,a0.w,a1.x,a1.y,a1.z,a1.w};
      float wv[8] = {w0.x,w0.y,w0.z,w0.w,w1.x,w1.y,w1.z,w1.w};
#pragma unroll
      for (int i = 0; i < 8; ++i)
#pragma unroll
        for (int j = 0; j < 8; ++j)
          acc[i][j] = fmaf(av[i], wv[j], acc[i][j]);
    }
  }

  // ---- epilogue ----
  const float* ub = Ub + t*64 + ob;
#pragma unroll
  for (int i = 0; i < 8; ++i){
    int n = blk*128 + nb + i;
    if (n < N){
      float* up = uout + (size_t)n*256 + t*64 + ob;
      float4 v0, v1;
      v0.x = acc[i][0] + ub[0]; v0.y = acc[i][1] + ub[1];
      v0.z = acc[i][2] + ub[2]; v0.w = acc[i][3] + ub[3];
      v1.x = acc[i][4] + ub[4]; v1.y = acc[i][5] + ub[5];
      v1.z = acc[i][6] + ub[6]; v1.w = acc[i][7] + ub[7];
      *(float4*)(up)     = v0;
      *(float4*)(up + 4) = v1;
    }
  }
}

// ---------- batchnorm stats (deterministic: fixed partials, no float atomics) ----------

__global__ __launch_bounds__(256) void k_bnstat(const float* __restrict__ u, float* __restrict__ part, int N){
  int c = threadIdx.x;
  int b = blockIdx.x;
  float s = 0.f, ss = 0.f;
  for (int n = b; n < N; n += gridDim.x){
    float v = u[(size_t)n*256 + c];
    s += v;
    ss = fmaf(v, v, ss);
  }
  part[(size_t)b*512 + c]       = s;
  part[(size_t)b*512 + 256 + c] = ss;
}

__global__ __launch_bounds__(256) void k_bnfin(const float* __restrict__ part, const float* __restrict__ gam,
                                               const float* __restrict__ bet, float* __restrict__ bnsc, int N){
  int c = threadIdx.x;
  float s = 0.f, ss = 0.f;
  for (int b = 0; b < BN_BLOCKS; ++b){
    s  += part[(size_t)b*512 + c];
    ss += part[(size_t)b*512 + 256 + c];
  }
  float invN = 1.f / (float)N;
  float mu  = s * invN;
  float ex2 = ss * invN;
  float var = fmaxf(ex2 - mu*mu, 0.f);
  float inv = 1.f / sqrtf(var + 1e-5f);
  float scale = gam[c] * inv;
  bnsc[c]       = scale;
  bnsc[256 + c] = bet[c] - mu*scale;
}

// ---------- mix GEMM + leaky + residual + relu (in-place on uo) ----------

#define ROW_FMA(WPTR, AV) { const float* __wr = (WPTR); \
  _Pragma("unroll") for (int c2 = 0; c2 < 64; ++c2) acc[c2] = fmaf(__wr[c2], (AV), acc[c2]); }

__global__ __launch_bounds__(256) void k_mix(float* uo, const float* __restrict__ bnsc,
                                             const float* __restrict__ mixT, const float* __restrict__ mixb,
                                             const float* __restrict__ nf, int N){
  int lane = threadIdx.x & 63;
  int w = __builtin_amdgcn_readfirstlane(threadIdx.x >> 6);
  int n = blockIdx.x*64 + lane;
  bool valid = (n < N);
  if (!valid) n = N - 1;
  float acc[64];
#pragma unroll
  for (int c2 = 0; c2 < 64; ++c2) acc[c2] = 0.f;
  const float* ur = uo + (size_t)n*256;
#pragma unroll 1
  for (int q = 0; q < 64; ++q){
    float4 u4 = *(const float4*)(ur + 4*q);
    float4 s4 = *(const float4*)(bnsc + 4*q);
    float4 h4 = *(const float4*)(bnsc + 256 + 4*q);
    float a0 = fmaf(u4.x, s4.x, h4.x);
    float a1 = fmaf(u4.y, s4.y, h4.y);
    float a2 = fmaf(u4.z, s4.z, h4.z);
    float a3 = fmaf(u4.w, s4.w, h4.w);
    const float* w0 = mixT + (size_t)(4*q)*256 + w*64;
    ROW_FMA(w0,       a0);
    ROW_FMA(w0 + 256, a1);
    ROW_FMA(w0 + 512, a2);
    ROW_FMA(w0 + 768, a3);
  }
  __syncthreads();   // all waves done READING u rows before any wave overwrites them
  if (valid){
    int j0 = w*64;
    const float* r = nf + (size_t)n*256 + j0;
    float* op = uo + (size_t)n*256 + j0;
#pragma unroll
    for (int c2 = 0; c2 < 64; c2 += 4){
      float4 v;
      float m0 = acc[c2]   + mixb[j0 + c2];
      float m1 = acc[c2+1] + mixb[j0 + c2 + 1];
      float m2 = acc[c2+2] + mixb[j0 + c2 + 2];
      float m3 = acc[c2+3] + mixb[j0 + c2 + 3];
      m0 = (m0 > 0.f) ? m0 : 0.01f*m0;
      m1 = (m1 > 0.f) ? m1 : 0.01f*m1;
      m2 = (m2 > 0.f) ? m2 : 0.01f*m2;
      m3 = (m3 > 0.f) ? m3 : 0.01f*m3;
      v.x = fmaxf(m0 + r[c2],   0.f);
      v.y = fmaxf(m1 + r[c2+1], 0.f);
      v.z = fmaxf(m2 + r[c2+2], 0.f);
      v.w = fmaxf(m3 + r[c2+3], 0.f);
      *(float4*)(op + c2) = v;
    }
  }
}

// ---------- host launcher ----------

extern "C" void kernel_launch(void* const* d_in, const int* in_sizes, int n_in,
                              void* d_out, int out_size, void* d_ws, size_t ws_size,
                              hipStream_t stream){
  const float* nf   = (const float*)d_in[0];
  const float* ef   = (const float*)d_in[1];
  const int*   srcv = (const int*)  d_in[2];
  const int*   dstv = (const int*)  d_in[3];
  const float* Mw   = (const float*)d_in[4];
  const float* Mb   = (const float*)d_in[5];
  const float* Uw   = (const float*)d_in[6];
  const float* Ub   = (const float*)d_in[7];
  const float* gam  = (const float*)d_in[8];
  const float* bet  = (const float*)d_in[9];
  const float* mixw = (const float*)d_in[10];
  const float* mixb = (const float*)d_in[11];
  int N = in_sizes[0] / 256;
  int E = in_sizes[2];
  float* out = (float*)d_out;

  char* wp = (char*)d_ws;
  auto alloc = [&](size_t bytes){
    char* p = wp;
    wp += (bytes + 1023) & ~(size_t)1023;
    return (void*)p;
  };
  int*   cnt   = (int*)  alloc((size_t)N*4);
  int*   offs  = (int*)  alloc((size_t)(N+1)*4);
  int*   cur   = (int*)  alloc((size_t)N*4);
  int*   bsum  = (int*)  alloc(256*4);
  int*   elist = (int*)  alloc((size_t)E*4);
  int*   esrc  = (int*)  alloc((size_t)E*4);
  float* efp   = (float*)alloc((size_t)E*32*4);
  float* A     = (float*)alloc((size_t)N*256*4);
  float* B     = (float*)alloc((size_t)N*256*4);
  float* agg   = (float*)alloc((size_t)N*1024*4);
  float* sc    = (float*)alloc((size_t)N*2*4);
  float* part  = (float*)alloc((size_t)BN_BLOCKS*512*4);
  float* bnsc  = (float*)alloc(512*4);
  float* UwT2  = (float*)alloc((size_t)832*256*4);
  float* mixT  = (float*)alloc((size_t)256*256*4);

  hipMemsetAsync(cnt,  0, (size_t)N*4,  stream);
  hipMemsetAsync(cur,  0, (size_t)N*4,  stream);

  k_tU  <<<(832*256 + 255)/256, 256, 0, stream>>>(Uw, UwT2);
  k_tM  <<<256, 256, 0, stream>>>(mixw, mixT);
  k_hist<<<(E + 255)/256, 256, 0, stream>>>(dstv, cnt, E);
  k_ab  <<<2048, 256, 0, stream>>>(nf, Mw, Mb, A, B, N);

  int NB = (N + 255)/256;
  k_scan1<<<NB, 256, 0, stream>>>(cnt, offs, bsum, N);
  k_scan2<<<1, 256, 0, stream>>>(bsum, NB);
  k_scan3<<<NB, 256, 0, stream>>>(offs, bsum, N, E);
  k_fill <<<(E + 255)/256, 256, 0, stream>>>(dstv, offs, cur, elist, E);
  k_perm <<<(E*8 + 255)/256, 256, 0, stream>>>(elist, srcv, ef, esrc, efp, E);

  k_agg<<<N, 256, 0, stream>>>(offs, esrc, efp, A, B, Mw, agg, sc, N);

  dim3 ugrid((N + 127)/128, 4);
  k_u<<<ugrid, 128, 0, stream>>>(nf, agg, sc, UwT2, Ub, out, N);

  k_bnstat<<<BN_BLOCKS, 256, 0, stream>>>(out, part, N);
  k_bnfin <<<1, 256, 0, stream>>>(part, gam, bet, bnsc, N);
  k_mix<<<(N + 63)/64, 256, 0, stream>>>(out, bnsc, mixT, mixb, nf, N);
}

// Round 6
// 726.143 us; speedup vs baseline: 1.4711x; 1.0388x over previous
//
#include <hip/hip_runtime.h>
#include <math.h>

constexpr float DELTA_ = 2.5f;
#define BN_BLOCKS 512

typedef __attribute__((ext_vector_type(8))) short bf16x8;
typedef __attribute__((ext_vector_type(4))) float f32x4;

__device__ inline ushort bf16h(float x){
  union { float f; unsigned u; } v; v.f = x;
  unsigned r = v.u + 0x7fffu + ((v.u >> 16) & 1u);
  return (ushort)(r >> 16);
}
__device__ inline float bf16f(ushort h){
  union { unsigned u; float f; } v; v.u = ((unsigned)h) << 16;
  return v.f;
}

// ---------- weight pre-pack for MFMA k_u ----------
// Wpk[t][kt][col][40] bf16-hi, col = path*64 + o, K rows are [h(64)|agg(256)] (320 total).
// path0: full [h|agg] weights; path1/2: agg*amp / agg*att weights with h-rows zeroed.
__global__ __launch_bounds__(256) void k_tU(const float* __restrict__ Uw, ushort* __restrict__ Wpk){
  int i = blockIdx.x*256 + threadIdx.x;
  if (i >= 4*10*192*40) return;
  int k   = i % 40;
  int col = (i/40) % 192;
  int kt  = (i/(40*192)) % 10;
  int t   = i/(40*192*10);
  float v = 0.f;
  if (k < 32){
    int kk = kt*32 + k;                 // 0..319
    int path = col >> 6, o = col & 63;
    int src = -1;
    if (kk < 64){ if (path == 0) src = kk; }          // h rows only feed path0
    else        { src = kk + path*256; }              // agg rows: +0/+256/+512
    if (src >= 0) v = Uw[((size_t)(t*64 + o))*832 + src];
  }
  Wpk[i] = bf16h(v);
}

__global__ __launch_bounds__(256) void k_tM(const float* __restrict__ Mx, float* __restrict__ MxT){
  int i = blockIdx.x*256 + threadIdx.x;            // i = k*256 + j
  if (i >= 256*256) return;
  int j = i & 255, k = i >> 8;
  MxT[i] = Mx[j*256 + k];
}

__global__ __launch_bounds__(256) void k_hist(const int* __restrict__ dstv, int* __restrict__ cnt, int E){
  int e = blockIdx.x*256 + threadIdx.x;
  if (e < E) atomicAdd(&cnt[dstv[e]], 1);
}

__global__ __launch_bounds__(256) void k_scan1(const int* __restrict__ cnt, int* __restrict__ offs,
                                               int* __restrict__ bsum, int N){
  __shared__ int lds[256];
  int i = threadIdx.x;
  int g = blockIdx.x*256 + i;
  int v = (g < N) ? cnt[g] : 0;
  int acc = v;
  lds[i] = acc; __syncthreads();
  for (int s = 1; s < 256; s <<= 1){
    int t = (i >= s) ? lds[i - s] : 0;
    __syncthreads();
    acc += t; lds[i] = acc;
    __syncthreads();
  }
  if (g < N) offs[g] = acc - v;
  if (i == 255) bsum[blockIdx.x] = acc;
}

__global__ __launch_bounds__(256) void k_scan2(int* __restrict__ bsum, int NB){
  __shared__ int lds[256];
  int i = threadIdx.x;
  int v = (i < NB) ? bsum[i] : 0;
  int acc = v;
  lds[i] = acc; __syncthreads();
  for (int s = 1; s < 256; s <<= 1){
    int t = (i >= s) ? lds[i - s] : 0;
    __syncthreads();
    acc += t; lds[i] = acc;
    __syncthreads();
  }
  if (i < NB) bsum[i] = acc - v;
}

__global__ __launch_bounds__(256) void k_scan3(int* __restrict__ offs, const int* __restrict__ bsum, int N, int E){
  int g = blockIdx.x*256 + threadIdx.x;
  if (g < N) offs[g] += bsum[blockIdx.x];
  if (g == 0) offs[N] = E;
}

__global__ __launch_bounds__(256) void k_fill(const int* __restrict__ dstv, const int* __restrict__ offs,
                                              int* __restrict__ cur, int* __restrict__ elist, int E){
  int e = blockIdx.x*256 + threadIdx.x;
  if (e < E){
    int d = dstv[e];
    elist[offs[d] + atomicAdd(&cur[d], 1)] = e;
  }
}

// ---------- permute srcv + edge features into CSR order ----------

__global__ __launch_bounds__(256) void k_perm(const int* __restrict__ elist, const int* __restrict__ srcv,
                                              const float* __restrict__ efeat,
                                              int* __restrict__ esrc, float* __restrict__ efp, int E){
  int g = blockIdx.x*256 + threadIdx.x;
  int pos = g >> 3;
  int q   = g & 7;
  if (pos >= E) return;
  int e = elist[pos];
  if (q == 0) esrc[pos] = srcv[e];
  float4 v = *(const float4*)(efeat + (size_t)e*32 + q*4);
  *(float4*)(efp + (size_t)pos*32 + q*4) = v;
}

// ---------- A = W_src*h, B = W_dst*h + M_b (per node) ----------

__global__ __launch_bounds__(256) void k_ab(const float* __restrict__ nf, const float* __restrict__ Mw,
                                            const float* __restrict__ Mb,
                                            float* __restrict__ A, float* __restrict__ B, int N){
  int c = threadIdx.x;
  int t = __builtin_amdgcn_readfirstlane(threadIdx.x >> 6);
  float ws[64], wd[64];
  const float* row = Mw + (size_t)c*160;
#pragma unroll
  for (int k = 0; k < 64; k += 4){
    float4 a = *(const float4*)(row + k);
    float4 b = *(const float4*)(row + 64 + k);
    ws[k]=a.x; ws[k+1]=a.y; ws[k+2]=a.z; ws[k+3]=a.w;
    wd[k]=b.x; wd[k+1]=b.y; wd[k+2]=b.z; wd[k+3]=b.w;
  }
  float bias = Mb[c];
  for (int n = blockIdx.x; n < N; n += gridDim.x){
    const float* h = nf + (size_t)n*256 + t*64;
    float sa = 0.f, sb = 0.f;
#pragma unroll
    for (int k = 0; k < 64; k += 4){
      float4 h4 = *(const float4*)(h + k);
      sa = fmaf(ws[k], h4.x, sa);  sb = fmaf(wd[k], h4.x, sb);
      sa = fmaf(ws[k+1], h4.y, sa); sb = fmaf(wd[k+1], h4.y, sb);
      sa = fmaf(ws[k+2], h4.z, sa); sb = fmaf(wd[k+2], h4.z, sb);
      sa = fmaf(ws[k+3], h4.w, sa); sb = fmaf(wd[k+3], h4.w, sb);
    }
    A[(size_t)n*256 + c] = sa;
    B[(size_t)n*256 + c] = sb + bias;
  }
}

// ---------- per-node aggregation: block = node, thread = channel ----------

__global__ __launch_bounds__(256) void k_agg(const int* __restrict__ offs, const int* __restrict__ esrc,
                                             const float* __restrict__ efp,
                                             const float* __restrict__ A, const float* __restrict__ B,
                                             const float* __restrict__ Mw,
                                             float* __restrict__ agg, float* __restrict__ sc, int N){
  int c = threadIdx.x;
  float4 wef[8];
  const float* wrow = Mw + (size_t)c*160 + 128;
#pragma unroll
  for (int q = 0; q < 8; ++q) wef[q] = *(const float4*)(wrow + 4*q);

  int n = blockIdx.x;
  if (n >= N) return;
  int o0 = __builtin_amdgcn_readfirstlane(offs[n]);
  int o1 = __builtin_amdgcn_readfirstlane(offs[n+1]);
  int cnt = o1 - o0;
  float b0 = B[(size_t)n*256 + c];
  float s = 0.f, ss = 0.f, mx = -__builtin_huge_valf(), mn = __builtin_huge_valf();

  int i = 0;
  for (; i + 4 <= cnt; i += 4){
    int p = o0 + i;
    int s0 = __builtin_amdgcn_readfirstlane(esrc[p+0]);
    int s1 = __builtin_amdgcn_readfirstlane(esrc[p+1]);
    int s2 = __builtin_amdgcn_readfirstlane(esrc[p+2]);
    int s3 = __builtin_amdgcn_readfirstlane(esrc[p+3]);
    const float* f0 = efp + (size_t)(p+0)*32;
    const float* f1 = efp + (size_t)(p+1)*32;
    const float* f2 = efp + (size_t)(p+2)*32;
    const float* f3 = efp + (size_t)(p+3)*32;
    float a0 = A[(size_t)s0*256 + c];
    float a1 = A[(size_t)s1*256 + c];
    float a2 = A[(size_t)s2*256 + c];
    float a3 = A[(size_t)s3*256 + c];
    float m0 = b0 + a0;
    float m1 = b0 + a1;
    float m2 = b0 + a2;
    float m3 = b0 + a3;
#pragma unroll
    for (int q = 0; q < 8; ++q){
      float4 e0 = *(const float4*)(f0 + 4*q);
      float4 e1 = *(const float4*)(f1 + 4*q);
      float4 e2 = *(const float4*)(f2 + 4*q);
      float4 e3 = *(const float4*)(f3 + 4*q);
      m0 = fmaf(e0.x, wef[q].x, m0); m0 = fmaf(e0.y, wef[q].y, m0);
      m0 = fmaf(e0.z, wef[q].z, m0); m0 = fmaf(e0.w, wef[q].w, m0);
      m1 = fmaf(e1.x, wef[q].x, m1); m1 = fmaf(e1.y, wef[q].y, m1);
      m1 = fmaf(e1.z, wef[q].z, m1); m1 = fmaf(e1.w, wef[q].w, m1);
      m2 = fmaf(e2.x, wef[q].x, m2); m2 = fmaf(e2.y, wef[q].y, m2);
      m2 = fmaf(e2.z, wef[q].z, m2); m2 = fmaf(e2.w, wef[q].w, m2);
      m3 = fmaf(e3.x, wef[q].x, m3); m3 = fmaf(e3.y, wef[q].y, m3);
      m3 = fmaf(e3.z, wef[q].z, m3); m3 = fmaf(e3.w, wef[q].w, m3);
    }
    s += m0; s += m1; s += m2; s += m3;
    ss = fmaf(m0, m0, ss); ss = fmaf(m1, m1, ss);
    ss = fmaf(m2, m2, ss); ss = fmaf(m3, m3, ss);
    mx = fmaxf(mx, fmaxf(fmaxf(m0, m1), fmaxf(m2, m3)));
    mn = fminf(mn, fminf(fminf(m0, m1), fminf(m2, m3)));
  }
  for (; i < cnt; ++i){
    int p = o0 + i;
    int sidx = __builtin_amdgcn_readfirstlane(esrc[p]);
    const float* ef = efp + (size_t)p*32;
    float m = b0 + A[(size_t)sidx*256 + c];
#pragma unroll
    for (int q = 0; q < 8; ++q){
      float4 e4 = *(const float4*)(ef + 4*q);
      m = fmaf(e4.x, wef[q].x, m);
      m = fmaf(e4.y, wef[q].y, m);
      m = fmaf(e4.z, wef[q].z, m);
      m = fmaf(e4.w, wef[q].w, m);
    }
    s += m;
    ss = fmaf(m, m, ss);
    mx = fmaxf(mx, m);
    mn = fminf(mn, m);
  }

  float deg  = (float)cnt;
  float degc = fmaxf(deg, 1.f);
  float inv  = 1.f / degc;
  float mean = s * inv;
  float var  = fmaxf(ss * inv - mean*mean, 0.f);
  float sd   = sqrtf(var + 1e-30f);
  if (cnt == 0){ mx = 0.f; mn = 0.f; }
  float* ar = agg + (size_t)n*1024 + (size_t)(c >> 6)*256 + (c & 63);
  ar[0]   = mean;
  ar[64]  = mx;
  ar[128] = mn;
  ar[192] = sd;
  if (c == 0){
    float logd = logf(deg + 1.f);
    sc[(size_t)n*2]     = logd * (1.f / DELTA_);
    sc[(size_t)n*2 + 1] = (cnt > 0) ? (DELTA_ / fmaxf(logd, 1e-12f)) : 0.f;
  }
}

// ---------- U GEMM via MFMA (split-bf16 2-term) ----------
// Per tower t: X[64 nodes][320] x W[320][192]; cols = [y1(64) | y2(64) | y3(64)],
// u = y1 + amp*y2 + att*y3 + Ub (amp/att commute out of the dot product).
// Block = 128 threads (2 waves); wave w owns cols [w*96, w*96+96).

struct SmemGemm {
  ushort a_hi[64][40];
  ushort a_lo[64][40];
  ushort b_hi[192][40];
};

__global__ __launch_bounds__(128) void k_u(const float* __restrict__ nf, const float* __restrict__ agg,
                                           const float* __restrict__ sc, const ushort* __restrict__ Wpk,
                                           const float* __restrict__ Ub, float* __restrict__ uout, int Nn){
  __shared__ union USm { SmemGemm s; float u[64][68]; } sm;

  int tid = threadIdx.x;
  int t   = blockIdx.y;
  int nbase = blockIdx.x * 64;
  int lane = tid & 63;
  int wv   = tid >> 6;
  int li = lane & 15, kc = lane >> 4;

  f32x4 acc[4][6];
#pragma unroll
  for (int ri = 0; ri < 4; ++ri)
#pragma unroll
    for (int ci = 0; ci < 6; ++ci) acc[ri][ci] = (f32x4)0.f;

  for (int kt = 0; kt < 10; ++kt){
    __syncthreads();
    // ---- stage A (64 nodes x 32 k), fp32 -> bf16 hi/lo ----
#pragma unroll
    for (int p = 0; p < 4; ++p){
      int idx = p*128 + tid;
      int node = idx >> 3, k4 = idx & 7;
      int gn = nbase + node; int gnc = (gn < Nn) ? gn : (Nn - 1);
      const float* srcp = (kt < 2) ? (nf  + (size_t)gnc*256  + t*64  + kt*32)
                                   : (agg + (size_t)gnc*1024 + t*256 + (size_t)(kt-2)*32);
      float4 v = *(const float4*)(srcp + k4*4);
      ushort4 hh, ll;
      hh.x = bf16h(v.x); hh.y = bf16h(v.y); hh.z = bf16h(v.z); hh.w = bf16h(v.w);
      ll.x = bf16h(v.x - bf16f(hh.x));
      ll.y = bf16h(v.y - bf16f(hh.y));
      ll.z = bf16h(v.z - bf16f(hh.z));
      ll.w = bf16h(v.w - bf16f(hh.w));
      *(ushort4*)(&sm.s.a_hi[node][k4*4]) = hh;
      *(ushort4*)(&sm.s.a_lo[node][k4*4]) = ll;
    }
    // ---- stage B (linear copy of pre-packed image) ----
    {
      const int4* wsrc = (const int4*)(Wpk + (((size_t)t*10 + kt)*192*40));
      int4* bdst = (int4*)(&sm.s.b_hi[0][0]);
      for (int idx = tid; idx < 960; idx += 128) bdst[idx] = wsrc[idx];
    }
    __syncthreads();

    // ---- fragments + MFMA ----
    bf16x8 ah[4], al[4];
#pragma unroll
    for (int ri = 0; ri < 4; ++ri){
      ah[ri] = *(const bf16x8*)(&sm.s.a_hi[ri*16 + li][kc*8]);
      al[ri] = *(const bf16x8*)(&sm.s.a_lo[ri*16 + li][kc*8]);
    }
#pragma unroll
    for (int ci = 0; ci < 6; ++ci){
      bf16x8 bh8 = *(const bf16x8*)(&sm.s.b_hi[(wv*6 + ci)*16 + li][kc*8]);
#pragma unroll
      for (int ri = 0; ri < 4; ++ri){
        acc[ri][ci] = __builtin_amdgcn_mfma_f32_16x16x32_bf16(ah[ri], bh8, acc[ri][ci], 0, 0, 0);
        acc[ri][ci] = __builtin_amdgcn_mfma_f32_16x16x32_bf16(al[ri], bh8, acc[ri][ci], 0, 0, 0);
      }
    }
  }

  // ---- epilogue: combine y1 + amp*y2 + att*y3 in LDS (phased, disjoint writes) ----
  __syncthreads();
  if (wv == 0){
    // base y1: waves-0 cols c=0..3 -> o = c*16
#pragma unroll
    for (int ri = 0; ri < 4; ++ri)
#pragma unroll
      for (int ci = 0; ci < 4; ++ci)
#pragma unroll
        for (int r = 0; r < 4; ++r)
          sm.u[ri*16 + kc*4 + r][ci*16 + li] = acc[ri][ci][r];
  }
  __syncthreads();

#define ADD_SCALED(CI, OBASE, SCOFF)                                              \
  {                                                                                \
    _Pragma("unroll")                                                              \
    for (int ri = 0; ri < 4; ++ri){                                                \
      _Pragma("unroll")                                                            \
      for (int r = 0; r < 4; ++r){                                                 \
        int node = ri*16 + kc*4 + r;                                               \
        int gn = nbase + node; int gnc = (gn < Nn) ? gn : (Nn - 1);                \
        float scl = sc[(size_t)gnc*2 + (SCOFF)];                                   \
        sm.u[node][(OBASE) + li] += scl * acc[ri][CI][r];                          \
      }                                                                            \
    }                                                                              \
  }

  // y2 (amp): wave0 cols c=4,5 (o 0..31); wave1 cols c=6,7 (o 32..63)
  if (wv == 0){
    ADD_SCALED(4, 0, 0);
    ADD_SCALED(5, 16, 0);
  } else {
    ADD_SCALED(0, 32, 0);
    ADD_SCALED(1, 48, 0);
  }
  __syncthreads();
  // y3 (att): wave1 cols c=8..11 (o 0..63)
  if (wv == 1){
    ADD_SCALED(2, 0, 1);
    ADD_SCALED(3, 16, 1);
    ADD_SCALED(4, 32, 1);
    ADD_SCALED(5, 48, 1);
  }
  __syncthreads();
#undef ADD_SCALED

  // ---- store u + Ub ----
  for (int idx = tid; idx < 64*16; idx += 128){
    int n = idx >> 4, o4 = (idx & 15)*4;
    int gn = nbase + n;
    if (gn < Nn){
      float4 v = *(float4*)(&sm.u[n][o4]);
      const float* ubp = Ub + t*64 + o4;
      v.x += ubp[0]; v.y += ubp[1]; v.z += ubp[2]; v.w += ubp[3];
      *(float4*)(&uout[(size_t)gn*256 + t*64 + o4]) = v;
    }
  }
}

// ---------- batchnorm stats (deterministic partials) ----------

__global__ __launch_bounds__(256) void k_bnstat(const float* __restrict__ u, float* __restrict__ part, int N){
  int c = threadIdx.x;
  int b = blockIdx.x;
  float s = 0.f, ss = 0.f;
  for (int n = b; n < N; n += gridDim.x){
    float v = u[(size_t)n*256 + c];
    s += v;
    ss = fmaf(v, v, ss);
  }
  part[(size_t)b*512 + c]       = s;
  part[(size_t)b*512 + 256 + c] = ss;
}

__global__ __launch_bounds__(256) void k_bnfin(const float* __restrict__ part, const float* __restrict__ gam,
                                               const float* __restrict__ bet, float* __restrict__ bnsc, int N){
  int c = threadIdx.x;
  float s = 0.f, ss = 0.f;
  for (int b = 0; b < BN_BLOCKS; ++b){
    s  += part[(size_t)b*512 + c];
    ss += part[(size_t)b*512 + 256 + c];
  }
  float invN = 1.f / (float)N;
  float mu  = s * invN;
  float ex2 = ss * invN;
  float var = fmaxf(ex2 - mu*mu, 0.f);
  float inv = 1.f / sqrtf(var + 1e-5f);
  float scale = gam[c] * inv;
  bnsc[c]       = scale;
  bnsc[256 + c] = bet[c] - mu*scale;
}

// ---------- mix GEMM + leaky + residual + relu (in-place on uo) ----------

#define ROW_FMA(WPTR, AV) { const float* __wr = (WPTR); \
  _Pragma("unroll") for (int c2 = 0; c2 < 64; ++c2) acc[c2] = fmaf(__wr[c2], (AV), acc[c2]); }

__global__ __launch_bounds__(256) void k_mix(float* uo, const float* __restrict__ bnsc,
                                             const float* __restrict__ mixT, const float* __restrict__ mixb,
                                             const float* __restrict__ nf, int N){
  int lane = threadIdx.x & 63;
  int w = __builtin_amdgcn_readfirstlane(threadIdx.x >> 6);
  int n = blockIdx.x*64 + lane;
  bool valid = (n < N);
  if (!valid) n = N - 1;
  float acc[64];
#pragma unroll
  for (int c2 = 0; c2 < 64; ++c2) acc[c2] = 0.f;
  const float* ur = uo + (size_t)n*256;
#pragma unroll 1
  for (int q = 0; q < 64; ++q){
    float4 u4 = *(const float4*)(ur + 4*q);
    float4 s4 = *(const float4*)(bnsc + 4*q);
    float4 h4 = *(const float4*)(bnsc + 256 + 4*q);
    float a0 = fmaf(u4.x, s4.x, h4.x);
    float a1 = fmaf(u4.y, s4.y, h4.y);
    float a2 = fmaf(u4.z, s4.z, h4.z);
    float a3 = fmaf(u4.w, s4.w, h4.w);
    const float* w0 = mixT + (size_t)(4*q)*256 + w*64;
    ROW_FMA(w0,       a0);
    ROW_FMA(w0 + 256, a1);
    ROW_FMA(w0 + 512, a2);
    ROW_FMA(w0 + 768, a3);
  }
  __syncthreads();
  if (valid){
    int j0 = w*64;
    const float* r = nf + (size_t)n*256 + j0;
    float* op = uo + (size_t)n*256 + j0;
#pragma unroll
    for (int c2 = 0; c2 < 64; c2 += 4){
      float4 v;
      float m0 = acc[c2]   + mixb[j0 + c2];
      float m1 = acc[c2+1] + mixb[j0 + c2 + 1];
      float m2 = acc[c2+2] + mixb[j0 + c2 + 2];
      float m3 = acc[c2+3] + mixb[j0 + c2 + 3];
      m0 = (m0 > 0.f) ? m0 : 0.01f*m0;
      m1 = (m1 > 0.f) ? m1 : 0.01f*m1;
      m2 = (m2 > 0.f) ? m2 : 0.01f*m2;
      m3 = (m3 > 0.f) ? m3 : 0.01f*m3;
      v.x = fmaxf(m0 + r[c2],   0.f);
      v.y = fmaxf(m1 + r[c2+1], 0.f);
      v.z = fmaxf(m2 + r[c2+2], 0.f);
      v.w = fmaxf(m3 + r[c2+3], 0.f);
      *(float4*)(op + c2) = v;
    }
  }
}

// ---------- host launcher ----------

extern "C" void kernel_launch(void* const* d_in, const int* in_sizes, int n_in,
                              void* d_out, int out_size, void* d_ws, size_t ws_size,
                              hipStream_t stream){
  const float* nf   = (const float*)d_in[0];
  const float* ef   = (const float*)d_in[1];
  const int*   srcv = (const int*)  d_in[2];
  const int*   dstv = (const int*)  d_in[3];
  const float* Mw   = (const float*)d_in[4];
  const float* Mb   = (const float*)d_in[5];
  const float* Uw   = (const float*)d_in[6];
  const float* Ub   = (const float*)d_in[7];
  const float* gam  = (const float*)d_in[8];
  const float* bet  = (const float*)d_in[9];
  const float* mixw = (const float*)d_in[10];
  const float* mixb = (const float*)d_in[11];
  int N = in_sizes[0] / 256;
  int E = in_sizes[2];
  float* out = (float*)d_out;

  char* wp = (char*)d_ws;
  auto alloc = [&](size_t bytes){
    char* p = wp;
    wp += (bytes + 1023) & ~(size_t)1023;
    return (void*)p;
  };
  int*    cnt   = (int*)   alloc((size_t)N*4);
  int*    offs  = (int*)   alloc((size_t)(N+1)*4);
  int*    cur   = (int*)   alloc((size_t)N*4);
  int*    bsum  = (int*)   alloc(256*4);
  int*    elist = (int*)   alloc((size_t)E*4);
  int*    esrc  = (int*)   alloc((size_t)E*4);
  float*  efp   = (float*) alloc((size_t)E*32*4);
  float*  A     = (float*) alloc((size_t)N*256*4);
  float*  B     = (float*) alloc((size_t)N*256*4);
  float*  agg   = (float*) alloc((size_t)N*1024*4);
  float*  sc    = (float*) alloc((size_t)N*2*4);
  float*  part  = (float*) alloc((size_t)BN_BLOCKS*512*4);
  float*  bnsc  = (float*) alloc(512*4);
  ushort* Wpk   = (ushort*)alloc((size_t)4*10*192*40*2);
  float*  mixT  = (float*) alloc((size_t)256*256*4);

  hipMemsetAsync(cnt,  0, (size_t)N*4,  stream);
  hipMemsetAsync(cur,  0, (size_t)N*4,  stream);

  k_tU  <<<(4*10*192*40 + 255)/256, 256, 0, stream>>>(Uw, Wpk);
  k_tM  <<<256, 256, 0, stream>>>(mixw, mixT);
  k_hist<<<(E + 255)/256, 256, 0, stream>>>(dstv, cnt, E);
  k_ab  <<<2048, 256, 0, stream>>>(nf, Mw, Mb, A, B, N);

  int NB = (N + 255)/256;
  k_scan1<<<NB, 256, 0, stream>>>(cnt, offs, bsum, N);
  k_scan2<<<1, 256, 0, stream>>>(bsum, NB);
  k_scan3<<<NB, 256, 0, stream>>>(offs, bsum, N, E);
  k_fill <<<(E + 255)/256, 256, 0, stream>>>(dstv, offs, cur, elist, E);
  k_perm <<<(E*8 + 255)/256, 256, 0, stream>>>(elist, srcv, ef, esrc, efp, E);

  k_agg<<<N, 256, 0, stream>>>(offs, esrc, efp, A, B, Mw, agg, sc, N);

  dim3 ugrid((N + 63)/64, 4);
  k_u<<<ugrid, 128, 0, stream>>>(nf, agg, sc, Wpk, Ub, out, N);

  k_bnstat<<<BN_BLOCKS, 256, 0, stream>>>(out, part, N);
  k_bnfin <<<1, 256, 0, stream>>>(part, gam, bet, bnsc, N);
  k_mix<<<(N + 63)/64, 256, 0, stream>>>(out, bnsc, mixT, mixb, nf, N);
}

// Round 7
// 530.210 us; speedup vs baseline: 2.0148x; 1.3695x over previous
//
#include <hip/hip_runtime.h>
#include <math.h>

constexpr float DELTA_ = 2.5f;
#define BN_BLOCKS 512

typedef __attribute__((ext_vector_type(8))) short bf16x8;
typedef __attribute__((ext_vector_type(4))) float f32x4;
typedef __attribute__((ext_vector_type(2))) _Float16 half2_t;

#if defined(__has_builtin)
#if __has_builtin(__builtin_amdgcn_fdot2)
#define DOT2(a,b,c) __builtin_amdgcn_fdot2((a),(b),(c),false)
#endif
#endif
#ifndef DOT2
#define DOT2(a,b,c) fmaf((float)(a).x,(float)(b).x, fmaf((float)(a).y,(float)(b).y,(c)))
#endif

__device__ inline ushort bf16h(float x){
  union { float f; unsigned u; } v; v.f = x;
  unsigned r = v.u + 0x7fffu + ((v.u >> 16) & 1u);
  return (ushort)(r >> 16);
}
__device__ inline float bf16f(ushort h){
  union { unsigned u; float f; } v; v.u = ((unsigned)h) << 16;
  return v.f;
}

// ---------- weight pre-pack for MFMA k_u ----------
__global__ __launch_bounds__(256) void k_tU(const float* __restrict__ Uw, ushort* __restrict__ Wpk){
  int i = blockIdx.x*256 + threadIdx.x;
  if (i >= 4*10*192*40) return;
  int k   = i % 40;
  int col = (i/40) % 192;
  int kt  = (i/(40*192)) % 10;
  int t   = i/(40*192*10);
  float v = 0.f;
  if (k < 32){
    int kk = kt*32 + k;
    int path = col >> 6, o = col & 63;
    int src = -1;
    if (kk < 64){ if (path == 0) src = kk; }
    else        { src = kk + path*256; }
    if (src >= 0) v = Uw[((size_t)(t*64 + o))*832 + src];
  }
  Wpk[i] = bf16h(v);
}

// ---------- weight pre-pack for MFMA k_mix: Mpk[kt][col][40] ----------
__global__ __launch_bounds__(256) void k_tMpk(const float* __restrict__ mixw, ushort* __restrict__ Mpk){
  int i = blockIdx.x*256 + threadIdx.x;
  if (i >= 8*256*40) return;
  int k   = i % 40;
  int col = (i/40) % 256;
  int kt  = i/(40*256);
  float v = 0.f;
  if (k < 32) v = mixw[(size_t)col*256 + kt*32 + k];
  Mpk[i] = bf16h(v);
}

// ---------- pack M edge-feature weights to f16: Mwefh[c][32] ----------
__global__ __launch_bounds__(256) void k_tE(const float* __restrict__ Mw, _Float16* __restrict__ Mwefh){
  int i = blockIdx.x*256 + threadIdx.x;
  if (i >= 256*32) return;
  int k = i & 31, c = i >> 5;
  Mwefh[i] = (_Float16)Mw[(size_t)c*160 + 128 + k];
}

__global__ __launch_bounds__(256) void k_hist(const int* __restrict__ dstv, int* __restrict__ cnt, int E){
  int e = blockIdx.x*256 + threadIdx.x;
  if (e < E) atomicAdd(&cnt[dstv[e]], 1);
}

__global__ __launch_bounds__(256) void k_scan1(const int* __restrict__ cnt, int* __restrict__ offs,
                                               int* __restrict__ bsum, int N){
  __shared__ int lds[256];
  int i = threadIdx.x;
  int g = blockIdx.x*256 + i;
  int v = (g < N) ? cnt[g] : 0;
  int acc = v;
  lds[i] = acc; __syncthreads();
  for (int s = 1; s < 256; s <<= 1){
    int t = (i >= s) ? lds[i - s] : 0;
    __syncthreads();
    acc += t; lds[i] = acc;
    __syncthreads();
  }
  if (g < N) offs[g] = acc - v;
  if (i == 255) bsum[blockIdx.x] = acc;
}

__global__ __launch_bounds__(256) void k_scan2(int* __restrict__ bsum, int NB){
  __shared__ int lds[256];
  int i = threadIdx.x;
  int v = (i < NB) ? bsum[i] : 0;
  int acc = v;
  lds[i] = acc; __syncthreads();
  for (int s = 1; s < 256; s <<= 1){
    int t = (i >= s) ? lds[i - s] : 0;
    __syncthreads();
    acc += t; lds[i] = acc;
    __syncthreads();
  }
  if (i < NB) bsum[i] = acc - v;
}

__global__ __launch_bounds__(256) void k_scan3(int* __restrict__ offs, const int* __restrict__ bsum, int N, int E){
  int g = blockIdx.x*256 + threadIdx.x;
  if (g < N) offs[g] += bsum[blockIdx.x];
  if (g == 0) offs[N] = E;
}

__global__ __launch_bounds__(256) void k_fill(const int* __restrict__ dstv, const int* __restrict__ offs,
                                              int* __restrict__ cur, int* __restrict__ elist, int E){
  int e = blockIdx.x*256 + threadIdx.x;
  if (e < E){
    int d = dstv[e];
    elist[offs[d] + atomicAdd(&cur[d], 1)] = e;
  }
}

// ---------- permute srcv + edge features (as f16) into CSR order ----------

__global__ __launch_bounds__(256) void k_perm(const int* __restrict__ elist, const int* __restrict__ srcv,
                                              const float* __restrict__ efeat,
                                              int* __restrict__ esrc, _Float16* __restrict__ efh, int E){
  int g = blockIdx.x*256 + threadIdx.x;
  int pos = g >> 3;
  int q   = g & 7;
  if (pos >= E) return;
  int e = elist[pos];
  if (q == 0) esrc[pos] = srcv[e];
  float4 v = *(const float4*)(efeat + (size_t)e*32 + q*4);
  union { ushort4 u; _Float16 h[4]; } cv;
  cv.h[0] = (_Float16)v.x; cv.h[1] = (_Float16)v.y;
  cv.h[2] = (_Float16)v.z; cv.h[3] = (_Float16)v.w;
  *(ushort4*)(efh + (size_t)pos*32 + q*4) = cv.u;
}

// ---------- A_h = f16(W_src*h), B = W_dst*h + M_b (per node) ----------

__global__ __launch_bounds__(256) void k_ab(const float* __restrict__ nf, const float* __restrict__ Mw,
                                            const float* __restrict__ Mb,
                                            _Float16* __restrict__ A_h, float* __restrict__ B, int N){
  int c = threadIdx.x;
  int t = __builtin_amdgcn_readfirstlane(threadIdx.x >> 6);
  float ws[64], wd[64];
  const float* row = Mw + (size_t)c*160;
#pragma unroll
  for (int k = 0; k < 64; k += 4){
    float4 a = *(const float4*)(row + k);
    float4 b = *(const float4*)(row + 64 + k);
    ws[k]=a.x; ws[k+1]=a.y; ws[k+2]=a.z; ws[k+3]=a.w;
    wd[k]=b.x; wd[k+1]=b.y; wd[k+2]=b.z; wd[k+3]=b.w;
  }
  float bias = Mb[c];
  for (int n = blockIdx.x; n < N; n += gridDim.x){
    const float* h = nf + (size_t)n*256 + t*64;
    float sa = 0.f, sb = 0.f;
#pragma unroll
    for (int k = 0; k < 64; k += 4){
      float4 h4 = *(const float4*)(h + k);
      sa = fmaf(ws[k], h4.x, sa);  sb = fmaf(wd[k], h4.x, sb);
      sa = fmaf(ws[k+1], h4.y, sa); sb = fmaf(wd[k+1], h4.y, sb);
      sa = fmaf(ws[k+2], h4.z, sa); sb = fmaf(wd[k+2], h4.z, sb);
      sa = fmaf(ws[k+3], h4.w, sa); sb = fmaf(wd[k+3], h4.w, sb);
    }
    A_h[(size_t)n*256 + c] = (_Float16)sa;
    B[(size_t)n*256 + c] = sb + bias;
  }
}

// ---------- per-node aggregation: block = node, thread = channel, f16 dot2 ----------

__global__ __launch_bounds__(256) void k_agg(const int* __restrict__ offs, const int* __restrict__ esrc,
                                             const _Float16* __restrict__ efh,
                                             const _Float16* __restrict__ A_h, const float* __restrict__ B,
                                             const _Float16* __restrict__ Mwefh,
                                             float* __restrict__ agg, float* __restrict__ sc, int N){
  int c = threadIdx.x;
  union Wu { int4 i[4]; half2_t h[16]; } wr;
  {
    const int4* wp = (const int4*)(Mwefh + (size_t)c*32);
    wr.i[0] = wp[0]; wr.i[1] = wp[1]; wr.i[2] = wp[2]; wr.i[3] = wp[3];
  }

  int n = blockIdx.x;
  if (n >= N) return;
  int o0 = __builtin_amdgcn_readfirstlane(offs[n]);
  int o1 = __builtin_amdgcn_readfirstlane(offs[n+1]);
  int cnt = o1 - o0;
  float b0 = B[(size_t)n*256 + c];
  float s = 0.f, ss = 0.f, mx = -__builtin_huge_valf(), mn = __builtin_huge_valf();

  union Eu { int4 i[4]; half2_t h[16]; };

  int i = 0;
  for (; i + 4 <= cnt; i += 4){
    int p = o0 + i;
    int s0 = __builtin_amdgcn_readfirstlane(esrc[p+0]);
    int s1 = __builtin_amdgcn_readfirstlane(esrc[p+1]);
    int s2 = __builtin_amdgcn_readfirstlane(esrc[p+2]);
    int s3 = __builtin_amdgcn_readfirstlane(esrc[p+3]);
    Eu e0, e1, e2, e3;
    {
      const int4* p0 = (const int4*)(efh + (size_t)(p+0)*32);
      const int4* p1 = (const int4*)(efh + (size_t)(p+1)*32);
      const int4* p2 = (const int4*)(efh + (size_t)(p+2)*32);
      const int4* p3 = (const int4*)(efh + (size_t)(p+3)*32);
#pragma unroll
      for (int q = 0; q < 4; ++q){ e0.i[q]=p0[q]; e1.i[q]=p1[q]; e2.i[q]=p2[q]; e3.i[q]=p3[q]; }
    }
    float a0 = (float)A_h[(size_t)s0*256 + c];
    float a1 = (float)A_h[(size_t)s1*256 + c];
    float a2 = (float)A_h[(size_t)s2*256 + c];
    float a3 = (float)A_h[(size_t)s3*256 + c];
    float m0 = b0 + a0;
    float m1 = b0 + a1;
    float m2 = b0 + a2;
    float m3 = b0 + a3;
#pragma unroll
    for (int q = 0; q < 16; ++q){
      m0 = DOT2(e0.h[q], wr.h[q], m0);
      m1 = DOT2(e1.h[q], wr.h[q], m1);
      m2 = DOT2(e2.h[q], wr.h[q], m2);
      m3 = DOT2(e3.h[q], wr.h[q], m3);
    }
    s += m0; s += m1; s += m2; s += m3;
    ss = fmaf(m0, m0, ss); ss = fmaf(m1, m1, ss);
    ss = fmaf(m2, m2, ss); ss = fmaf(m3, m3, ss);
    mx = fmaxf(mx, fmaxf(fmaxf(m0, m1), fmaxf(m2, m3)));
    mn = fminf(mn, fminf(fminf(m0, m1), fminf(m2, m3)));
  }
  for (; i < cnt; ++i){
    int p = o0 + i;
    int sidx = __builtin_amdgcn_readfirstlane(esrc[p]);
    Eu e0;
    {
      const int4* p0 = (const int4*)(efh + (size_t)p*32);
#pragma unroll
      for (int q = 0; q < 4; ++q) e0.i[q] = p0[q];
    }
    float m = b0 + (float)A_h[(size_t)sidx*256 + c];
#pragma unroll
    for (int q = 0; q < 16; ++q) m = DOT2(e0.h[q], wr.h[q], m);
    s += m;
    ss = fmaf(m, m, ss);
    mx = fmaxf(mx, m);
    mn = fminf(mn, m);
  }

  float deg  = (float)cnt;
  float degc = fmaxf(deg, 1.f);
  float inv  = 1.f / degc;
  float mean = s * inv;
  float var  = fmaxf(ss * inv - mean*mean, 0.f);
  float sd   = sqrtf(var + 1e-30f);
  if (cnt == 0){ mx = 0.f; mn = 0.f; }
  float* ar = agg + (size_t)n*1024 + (size_t)(c >> 6)*256 + (c & 63);
  ar[0]   = mean;
  ar[64]  = mx;
  ar[128] = mn;
  ar[192] = sd;
  if (c == 0){
    float logd = logf(deg + 1.f);
    sc[(size_t)n*2]     = logd * (1.f / DELTA_);
    sc[(size_t)n*2 + 1] = (cnt > 0) ? (DELTA_ / fmaxf(logd, 1e-12f)) : 0.f;
  }
}

// ---------- U GEMM via MFMA (split-bf16 2-term, scaler-commuted paths) ----------

struct SmemGemm {
  ushort a_hi[64][40];
  ushort a_lo[64][40];
  ushort b_hi[192][40];
};

__global__ __launch_bounds__(128) void k_u(const float* __restrict__ nf, const float* __restrict__ agg,
                                           const float* __restrict__ sc, const ushort* __restrict__ Wpk,
                                           const float* __restrict__ Ub, float* __restrict__ uout, int Nn){
  __shared__ union USm { SmemGemm s; float u[64][68]; } sm;

  int tid = threadIdx.x;
  int t   = blockIdx.y;
  int nbase = blockIdx.x * 64;
  int lane = tid & 63;
  int wv   = tid >> 6;
  int li = lane & 15, kc = lane >> 4;

  f32x4 acc[4][6];
#pragma unroll
  for (int ri = 0; ri < 4; ++ri)
#pragma unroll
    for (int ci = 0; ci < 6; ++ci) acc[ri][ci] = (f32x4)0.f;

  for (int kt = 0; kt < 10; ++kt){
    __syncthreads();
#pragma unroll
    for (int p = 0; p < 4; ++p){
      int idx = p*128 + tid;
      int node = idx >> 3, k4 = idx & 7;
      int gn = nbase + node; int gnc = (gn < Nn) ? gn : (Nn - 1);
      const float* srcp = (kt < 2) ? (nf  + (size_t)gnc*256  + t*64  + kt*32)
                                   : (agg + (size_t)gnc*1024 + t*256 + (size_t)(kt-2)*32);
      float4 v = *(const float4*)(srcp + k4*4);
      ushort4 hh, ll;
      hh.x = bf16h(v.x); hh.y = bf16h(v.y); hh.z = bf16h(v.z); hh.w = bf16h(v.w);
      ll.x = bf16h(v.x - bf16f(hh.x));
      ll.y = bf16h(v.y - bf16f(hh.y));
      ll.z = bf16h(v.z - bf16f(hh.z));
      ll.w = bf16h(v.w - bf16f(hh.w));
      *(ushort4*)(&sm.s.a_hi[node][k4*4]) = hh;
      *(ushort4*)(&sm.s.a_lo[node][k4*4]) = ll;
    }
    {
      const int4* wsrc = (const int4*)(Wpk + (((size_t)t*10 + kt)*192*40));
      int4* bdst = (int4*)(&sm.s.b_hi[0][0]);
      for (int idx = tid; idx < 960; idx += 128) bdst[idx] = wsrc[idx];
    }
    __syncthreads();

    bf16x8 ah[4], al[4];
#pragma unroll
    for (int ri = 0; ri < 4; ++ri){
      ah[ri] = *(const bf16x8*)(&sm.s.a_hi[ri*16 + li][kc*8]);
      al[ri] = *(const bf16x8*)(&sm.s.a_lo[ri*16 + li][kc*8]);
    }
#pragma unroll
    for (int ci = 0; ci < 6; ++ci){
      bf16x8 bh8 = *(const bf16x8*)(&sm.s.b_hi[(wv*6 + ci)*16 + li][kc*8]);
#pragma unroll
      for (int ri = 0; ri < 4; ++ri){
        acc[ri][ci] = __builtin_amdgcn_mfma_f32_16x16x32_bf16(ah[ri], bh8, acc[ri][ci], 0, 0, 0);
        acc[ri][ci] = __builtin_amdgcn_mfma_f32_16x16x32_bf16(al[ri], bh8, acc[ri][ci], 0, 0, 0);
      }
    }
  }

  __syncthreads();
  if (wv == 0){
#pragma unroll
    for (int ri = 0; ri < 4; ++ri)
#pragma unroll
      for (int ci = 0; ci < 4; ++ci)
#pragma unroll
        for (int r = 0; r < 4; ++r)
          sm.u[ri*16 + kc*4 + r][ci*16 + li] = acc[ri][ci][r];
  }
  __syncthreads();

#define ADD_SCALED(CI, OBASE, SCOFF)                                              \
  {                                                                                \
    _Pragma("unroll")                                                              \
    for (int ri = 0; ri < 4; ++ri){                                                \
      _Pragma("unroll")                                                            \
      for (int r = 0; r < 4; ++r){                                                 \
        int node = ri*16 + kc*4 + r;                                               \
        int gn = nbase + node; int gnc = (gn < Nn) ? gn : (Nn - 1);                \
        float scl = sc[(size_t)gnc*2 + (SCOFF)];                                   \
        sm.u[node][(OBASE) + li] += scl * acc[ri][CI][r];                          \
      }                                                                            \
    }                                                                              \
  }

  if (wv == 0){
    ADD_SCALED(4, 0, 0);
    ADD_SCALED(5, 16, 0);
  } else {
    ADD_SCALED(0, 32, 0);
    ADD_SCALED(1, 48, 0);
  }
  __syncthreads();
  if (wv == 1){
    ADD_SCALED(2, 0, 1);
    ADD_SCALED(3, 16, 1);
    ADD_SCALED(4, 32, 1);
    ADD_SCALED(5, 48, 1);
  }
  __syncthreads();
#undef ADD_SCALED

  for (int idx = tid; idx < 64*16; idx += 128){
    int n = idx >> 4, o4 = (idx & 15)*4;
    int gn = nbase + n;
    if (gn < Nn){
      float4 v = *(float4*)(&sm.u[n][o4]);
      const float* ubp = Ub + t*64 + o4;
      v.x += ubp[0]; v.y += ubp[1]; v.z += ubp[2]; v.w += ubp[3];
      *(float4*)(&uout[(size_t)gn*256 + t*64 + o4]) = v;
    }
  }
}

// ---------- batchnorm stats (deterministic partials) ----------

__global__ __launch_bounds__(256) void k_bnstat(const float* __restrict__ u, float* __restrict__ part, int N){
  int c = threadIdx.x;
  int b = blockIdx.x;
  float s = 0.f, ss = 0.f;
  for (int n = b; n < N; n += gridDim.x){
    float v = u[(size_t)n*256 + c];
    s += v;
    ss = fmaf(v, v, ss);
  }
  part[(size_t)b*512 + c]       = s;
  part[(size_t)b*512 + 256 + c] = ss;
}

__global__ __launch_bounds__(256) void k_bnfin(const float* __restrict__ part, const float* __restrict__ gam,
                                               const float* __restrict__ bet, float* __restrict__ bnsc, int N){
  int c = threadIdx.x;
  float s = 0.f, ss = 0.f;
  for (int b = 0; b < BN_BLOCKS; ++b){
    s  += part[(size_t)b*512 + c];
    ss += part[(size_t)b*512 + 256 + c];
  }
  float invN = 1.f / (float)N;
  float mu  = s * invN;
  float ex2 = ss * invN;
  float var = fmaxf(ex2 - mu*mu, 0.f);
  float inv = 1.f / sqrtf(var + 1e-5f);
  float scale = gam[c] * inv;
  bnsc[c]       = scale;
  bnsc[256 + c] = bet[c] - mu*scale;
}

// ---------- mix GEMM via MFMA (split-bf16, BN folded into A-stage) ----------
// Block: 64 nodes x 256 cols, K=256 in 8 steps. In-place safe: each block
// reads only its own 64 u-rows (all during kt loop) and writes them at the end.

struct MixSm {
  ushort a_hi[64][40];
  ushort a_lo[64][40];
  ushort b_hi[256][40];
};

__global__ __launch_bounds__(256) void k_mix(const float* __restrict__ uo, float* __restrict__ outp,
                                             const float* __restrict__ bnsc,
                                             const ushort* __restrict__ Mpk, const float* __restrict__ mixb,
                                             const float* __restrict__ nf, int Nn){
  __shared__ MixSm sm;
  int tid = threadIdx.x;
  int nbase = blockIdx.x*64;
  int lane = tid & 63, wv = tid >> 6;
  int li = lane & 15, kc = lane >> 4;

  f32x4 acc[4][4];
#pragma unroll
  for (int ri = 0; ri < 4; ++ri)
#pragma unroll
    for (int ci = 0; ci < 4; ++ci) acc[ri][ci] = (f32x4)0.f;

  for (int kt = 0; kt < 8; ++kt){
    __syncthreads();
#pragma unroll
    for (int p = 0; p < 2; ++p){
      int idx = p*256 + tid;
      int node = idx >> 3, k4 = idx & 7;
      int gn = nbase + node; int gnc = (gn < Nn) ? gn : (Nn - 1);
      float4 v = *(const float4*)(uo + (size_t)gnc*256 + kt*32 + k4*4);
      float4 s4 = *(const float4*)(bnsc + kt*32 + k4*4);
      float4 h4 = *(const float4*)(bnsc + 256 + kt*32 + k4*4);
      float x0 = fmaf(v.x, s4.x, h4.x);
      float x1 = fmaf(v.y, s4.y, h4.y);
      float x2 = fmaf(v.z, s4.z, h4.z);
      float x3 = fmaf(v.w, s4.w, h4.w);
      ushort4 hh, ll;
      hh.x = bf16h(x0); hh.y = bf16h(x1); hh.z = bf16h(x2); hh.w = bf16h(x3);
      ll.x = bf16h(x0 - bf16f(hh.x));
      ll.y = bf16h(x1 - bf16f(hh.y));
      ll.z = bf16h(x2 - bf16f(hh.z));
      ll.w = bf16h(x3 - bf16f(hh.w));
      *(ushort4*)(&sm.a_hi[node][k4*4]) = hh;
      *(ushort4*)(&sm.a_lo[node][k4*4]) = ll;
    }
    {
      const int4* wsrc = (const int4*)(Mpk + (size_t)kt*256*40);
      int4* bdst = (int4*)(&sm.b_hi[0][0]);
      for (int idx = tid; idx < 1280; idx += 256) bdst[idx] = wsrc[idx];
    }
    __syncthreads();

    bf16x8 ah[4], al[4];
#pragma unroll
    for (int ri = 0; ri < 4; ++ri){
      ah[ri] = *(const bf16x8*)(&sm.a_hi[ri*16 + li][kc*8]);
      al[ri] = *(const bf16x8*)(&sm.a_lo[ri*16 + li][kc*8]);
    }
#pragma unroll
    for (int ci = 0; ci < 4; ++ci){
      bf16x8 bh = *(const bf16x8*)(&sm.b_hi[(wv*4 + ci)*16 + li][kc*8]);
#pragma unroll
      for (int ri = 0; ri < 4; ++ri){
        acc[ri][ci] = __builtin_amdgcn_mfma_f32_16x16x32_bf16(ah[ri], bh, acc[ri][ci], 0, 0, 0);
        acc[ri][ci] = __builtin_amdgcn_mfma_f32_16x16x32_bf16(al[ri], bh, acc[ri][ci], 0, 0, 0);
      }
    }
  }

  // epilogue: bias + leaky + residual + relu, direct store
#pragma unroll
  for (int ri = 0; ri < 4; ++ri){
#pragma unroll
    for (int r = 0; r < 4; ++r){
      int node = ri*16 + kc*4 + r;
      int gn = nbase + node;
      if (gn < Nn){
#pragma unroll
        for (int ci = 0; ci < 4; ++ci){
          int col = wv*64 + ci*16 + li;
          float m = acc[ri][ci][r] + mixb[col];
          m = (m > 0.f) ? m : 0.01f*m;
          float o = m + nf[(size_t)gn*256 + col];
          outp[(size_t)gn*256 + col] = fmaxf(o, 0.f);
        }
      }
    }
  }
}

// ---------- host launcher ----------

extern "C" void kernel_launch(void* const* d_in, const int* in_sizes, int n_in,
                              void* d_out, int out_size, void* d_ws, size_t ws_size,
                              hipStream_t stream){
  const float* nf   = (const float*)d_in[0];
  const float* ef   = (const float*)d_in[1];
  const int*   srcv = (const int*)  d_in[2];
  const int*   dstv = (const int*)  d_in[3];
  const float* Mw   = (const float*)d_in[4];
  const float* Mb   = (const float*)d_in[5];
  const float* Uw   = (const float*)d_in[6];
  const float* Ub   = (const float*)d_in[7];
  const float* gam  = (const float*)d_in[8];
  const float* bet  = (const float*)d_in[9];
  const float* mixw = (const float*)d_in[10];
  const float* mixb = (const float*)d_in[11];
  int N = in_sizes[0] / 256;
  int E = in_sizes[2];
  float* out = (float*)d_out;

  char* wp = (char*)d_ws;
  auto alloc = [&](size_t bytes){
    char* p = wp;
    wp += (bytes + 1023) & ~(size_t)1023;
    return (void*)p;
  };
  int*      cnt   = (int*)     alloc((size_t)N*4);
  int*      offs  = (int*)     alloc((size_t)(N+1)*4);
  int*      cur   = (int*)     alloc((size_t)N*4);
  int*      bsum  = (int*)     alloc(256*4);
  int*      elist = (int*)     alloc((size_t)E*4);
  int*      esrc  = (int*)     alloc((size_t)E*4);
  _Float16* efh   = (_Float16*)alloc((size_t)E*32*2);
  _Float16* A_h   = (_Float16*)alloc((size_t)N*256*2);
  float*    B     = (float*)   alloc((size_t)N*256*4);
  float*    agg   = (float*)   alloc((size_t)N*1024*4);
  float*    sc    = (float*)   alloc((size_t)N*2*4);
  float*    part  = (float*)   alloc((size_t)BN_BLOCKS*512*4);
  float*    bnsc  = (float*)   alloc(512*4);
  ushort*   Wpk   = (ushort*)  alloc((size_t)4*10*192*40*2);
  ushort*   Mpk   = (ushort*)  alloc((size_t)8*256*40*2);
  _Float16* Mwefh = (_Float16*)alloc((size_t)256*32*2);

  hipMemsetAsync(cnt,  0, (size_t)N*4,  stream);
  hipMemsetAsync(cur,  0, (size_t)N*4,  stream);

  k_tU  <<<(4*10*192*40 + 255)/256, 256, 0, stream>>>(Uw, Wpk);
  k_tMpk<<<(8*256*40 + 255)/256, 256, 0, stream>>>(mixw, Mpk);
  k_tE  <<<(256*32 + 255)/256, 256, 0, stream>>>(Mw, Mwefh);
  k_hist<<<(E + 255)/256, 256, 0, stream>>>(dstv, cnt, E);
  k_ab  <<<2048, 256, 0, stream>>>(nf, Mw, Mb, A_h, B, N);

  int NB = (N + 255)/256;
  k_scan1<<<NB, 256, 0, stream>>>(cnt, offs, bsum, N);
  k_scan2<<<1, 256, 0, stream>>>(bsum, NB);
  k_scan3<<<NB, 256, 0, stream>>>(offs, bsum, N, E);
  k_fill <<<(E + 255)/256, 256, 0, stream>>>(dstv, offs, cur, elist, E);
  k_perm <<<(E*8 + 255)/256, 256, 0, stream>>>(elist, srcv, ef, esrc, efh, E);

  k_agg<<<N, 256, 0, stream>>>(offs, esrc, efh, A_h, B, Mwefh, agg, sc, N);

  dim3 ugrid((N + 63)/64, 4);
  k_u<<<ugrid, 128, 0, stream>>>(nf, agg, sc, Wpk, Ub, out, N);

  k_bnstat<<<BN_BLOCKS, 256, 0, stream>>>(out, part, N);
  k_bnfin <<<1, 256, 0, stream>>>(part, gam, bet, bnsc, N);
  k_mix<<<(N + 63)/64, 256, 0, stream>>>(out, out, bnsc, Mpk, mixb, nf, N);
}

// Round 8
// 493.766 us; speedup vs baseline: 2.1635x; 1.0738x over previous
//
#include <hip/hip_runtime.h>
#include <math.h>

constexpr float DELTA_ = 2.5f;
#define BN_BLOCKS 512

typedef __attribute__((ext_vector_type(8))) short bf16x8;
typedef __attribute__((ext_vector_type(4))) float f32x4;
typedef __attribute__((ext_vector_type(2))) _Float16 half2_t;

#if defined(__has_builtin)
#if __has_builtin(__builtin_amdgcn_fdot2)
#define DOT2(a,b,c) __builtin_amdgcn_fdot2((a),(b),(c),false)
#endif
#endif
#ifndef DOT2
#define DOT2(a,b,c) fmaf((float)(a).x,(float)(b).x, fmaf((float)(a).y,(float)(b).y,(c)))
#endif

__device__ inline ushort bf16h(float x){
  union { float f; unsigned u; } v; v.f = x;
  unsigned r = v.u + 0x7fffu + ((v.u >> 16) & 1u);
  return (ushort)(r >> 16);
}
__device__ inline float bf16f(ushort h){
  union { unsigned u; float f; } v; v.u = ((unsigned)h) << 16;
  return v.f;
}

// ---------- U-weights: Wpk2[t][192][320] bf16 (col = path*64+o; path1/2 zero h-rows) ----------
__global__ __launch_bounds__(256) void k_tU(const float* __restrict__ Uw, ushort* __restrict__ Wpk2){
  int i = blockIdx.x*256 + threadIdx.x;          // i = (t*192+col)*320 + k
  if (i >= 4*192*320) return;
  int k   = i % 320;
  int col = (i/320) % 192;
  int t   = i/(320*192);
  int path = col >> 6, o = col & 63;
  float v = 0.f;
  int src = -1;
  if (k < 64){ if (path == 0) src = k; }
  else        src = k + path*256;
  if (src >= 0) v = Uw[((size_t)(t*64 + o))*832 + src];
  Wpk2[i] = bf16h(v);
}

// ---------- mix weights: Wm2[col][256] bf16 (mixw is [out][in] row-major) ----------
__global__ __launch_bounds__(256) void k_tMm(const float* __restrict__ mixw, ushort* __restrict__ Wm2){
  int i = blockIdx.x*256 + threadIdx.x;
  if (i >= 256*256) return;
  Wm2[i] = bf16h(mixw[i]);
}

// ---------- M edge-feature weights to f16 ----------
__global__ __launch_bounds__(256) void k_tE(const float* __restrict__ Mw, _Float16* __restrict__ Mwefh){
  int i = blockIdx.x*256 + threadIdx.x;
  if (i >= 256*32) return;
  int k = i & 31, c = i >> 5;
  Mwefh[i] = (_Float16)Mw[(size_t)c*160 + 128 + k];
}

// ---------- X2 h-part: X2[n][t][j][hi8|lo8] for k=0..63 ----------
__global__ __launch_bounds__(256) void k_xh(const float* __restrict__ nf, ushort* __restrict__ X2, int N){
  for (long i = blockIdx.x*256 + threadIdx.x; i < (long)N*256; i += (long)gridDim.x*256){
    int n = (int)(i >> 8), c = (int)(i & 255);
    int t = c >> 6, d = c & 63;
    int j = d >> 3, pos = d & 7;
    float v = nf[i];
    ushort hi = bf16h(v);
    size_t base = (((size_t)n*4 + t)*40 + j)*16;
    X2[base + pos]     = hi;
    X2[base + 8 + pos] = bf16h(v - bf16f(hi));
  }
}

__global__ __launch_bounds__(256) void k_hist(const int* __restrict__ dstv, int* __restrict__ cnt, int E){
  int e = blockIdx.x*256 + threadIdx.x;
  if (e < E) atomicAdd(&cnt[dstv[e]], 1);
}

__global__ __launch_bounds__(256) void k_scan1(const int* __restrict__ cnt, int* __restrict__ offs,
                                               int* __restrict__ bsum, int N){
  __shared__ int lds[256];
  int i = threadIdx.x;
  int g = blockIdx.x*256 + i;
  int v = (g < N) ? cnt[g] : 0;
  int acc = v;
  lds[i] = acc; __syncthreads();
  for (int s = 1; s < 256; s <<= 1){
    int t = (i >= s) ? lds[i - s] : 0;
    __syncthreads();
    acc += t; lds[i] = acc;
    __syncthreads();
  }
  if (g < N) offs[g] = acc - v;
  if (i == 255) bsum[blockIdx.x] = acc;
}

__global__ __launch_bounds__(256) void k_scan2(int* __restrict__ bsum, int NB){
  __shared__ int lds[256];
  int i = threadIdx.x;
  int v = (i < NB) ? bsum[i] : 0;
  int acc = v;
  lds[i] = acc; __syncthreads();
  for (int s = 1; s < 256; s <<= 1){
    int t = (i >= s) ? lds[i - s] : 0;
    __syncthreads();
    acc += t; lds[i] = acc;
    __syncthreads();
  }
  if (i < NB) bsum[i] = acc - v;
}

__global__ __launch_bounds__(256) void k_scan3(int* __restrict__ offs, const int* __restrict__ bsum, int N, int E){
  int g = blockIdx.x*256 + threadIdx.x;
  if (g < N) offs[g] += bsum[blockIdx.x];
  if (g == 0) offs[N] = E;
}

__global__ __launch_bounds__(256) void k_fill(const int* __restrict__ dstv, const int* __restrict__ offs,
                                              int* __restrict__ cur, int* __restrict__ elist, int E){
  int e = blockIdx.x*256 + threadIdx.x;
  if (e < E){
    int d = dstv[e];
    elist[offs[d] + atomicAdd(&cur[d], 1)] = e;
  }
}

// ---------- permute srcv + edge features (f16) into CSR order ----------
__global__ __launch_bounds__(256) void k_perm(const int* __restrict__ elist, const int* __restrict__ srcv,
                                              const float* __restrict__ efeat,
                                              int* __restrict__ esrc, _Float16* __restrict__ efh, int E){
  int g = blockIdx.x*256 + threadIdx.x;
  int pos = g >> 3;
  int q   = g & 7;
  if (pos >= E) return;
  int e = elist[pos];
  if (q == 0) esrc[pos] = srcv[e];
  float4 v = *(const float4*)(efeat + (size_t)e*32 + q*4);
  union { ushort4 u; _Float16 h[4]; } cv;
  cv.h[0] = (_Float16)v.x; cv.h[1] = (_Float16)v.y;
  cv.h[2] = (_Float16)v.z; cv.h[3] = (_Float16)v.w;
  *(ushort4*)(efh + (size_t)pos*32 + q*4) = cv.u;
}

// ---------- A_h = f16(W_src*h), B = W_dst*h + M_b ----------
__global__ __launch_bounds__(256) void k_ab(const float* __restrict__ nf, const float* __restrict__ Mw,
                                            const float* __restrict__ Mb,
                                            _Float16* __restrict__ A_h, float* __restrict__ B, int N){
  int c = threadIdx.x;
  int t = __builtin_amdgcn_readfirstlane(threadIdx.x >> 6);
  float ws[64], wd[64];
  const float* row = Mw + (size_t)c*160;
#pragma unroll
  for (int k = 0; k < 64; k += 4){
    float4 a = *(const float4*)(row + k);
    float4 b = *(const float4*)(row + 64 + k);
    ws[k]=a.x; ws[k+1]=a.y; ws[k+2]=a.z; ws[k+3]=a.w;
    wd[k]=b.x; wd[k+1]=b.y; wd[k+2]=b.z; wd[k+3]=b.w;
  }
  float bias = Mb[c];
  for (int n = blockIdx.x; n < N; n += gridDim.x){
    const float* h = nf + (size_t)n*256 + t*64;
    float sa = 0.f, sb = 0.f;
#pragma unroll
    for (int k = 0; k < 64; k += 4){
      float4 h4 = *(const float4*)(h + k);
      sa = fmaf(ws[k], h4.x, sa);  sb = fmaf(wd[k], h4.x, sb);
      sa = fmaf(ws[k+1], h4.y, sa); sb = fmaf(wd[k+1], h4.y, sb);
      sa = fmaf(ws[k+2], h4.z, sa); sb = fmaf(wd[k+2], h4.z, sb);
      sa = fmaf(ws[k+3], h4.w, sa); sb = fmaf(wd[k+3], h4.w, sb);
    }
    A_h[(size_t)n*256 + c] = (_Float16)sa;
    B[(size_t)n*256 + c] = sb + bias;
  }
}

// ---------- per-node aggregation (f16 dot2), writes X2 agg-part hi/lo directly ----------
__global__ __launch_bounds__(256) void k_agg(const int* __restrict__ offs, const int* __restrict__ esrc,
                                             const _Float16* __restrict__ efh,
                                             const _Float16* __restrict__ A_h, const float* __restrict__ B,
                                             const _Float16* __restrict__ Mwefh,
                                             ushort* __restrict__ X2, float* __restrict__ sc, int N){
  int c = threadIdx.x;
  union Wu { int4 i[4]; half2_t h[16]; } wr;
  {
    const int4* wp = (const int4*)(Mwefh + (size_t)c*32);
    wr.i[0] = wp[0]; wr.i[1] = wp[1]; wr.i[2] = wp[2]; wr.i[3] = wp[3];
  }

  int n = blockIdx.x;
  if (n >= N) return;
  int o0 = __builtin_amdgcn_readfirstlane(offs[n]);
  int o1 = __builtin_amdgcn_readfirstlane(offs[n+1]);
  int cnt = o1 - o0;
  float b0 = B[(size_t)n*256 + c];
  float s = 0.f, ss = 0.f, mx = -__builtin_huge_valf(), mn = __builtin_huge_valf();

  union Eu { int4 i[4]; half2_t h[16]; };

  int i = 0;
  for (; i + 4 <= cnt; i += 4){
    int p = o0 + i;
    int s0 = __builtin_amdgcn_readfirstlane(esrc[p+0]);
    int s1 = __builtin_amdgcn_readfirstlane(esrc[p+1]);
    int s2 = __builtin_amdgcn_readfirstlane(esrc[p+2]);
    int s3 = __builtin_amdgcn_readfirstlane(esrc[p+3]);
    Eu e0, e1, e2, e3;
    {
      const int4* p0 = (const int4*)(efh + (size_t)(p+0)*32);
      const int4* p1 = (const int4*)(efh + (size_t)(p+1)*32);
      const int4* p2 = (const int4*)(efh + (size_t)(p+2)*32);
      const int4* p3 = (const int4*)(efh + (size_t)(p+3)*32);
#pragma unroll
      for (int q = 0; q < 4; ++q){ e0.i[q]=p0[q]; e1.i[q]=p1[q]; e2.i[q]=p2[q]; e3.i[q]=p3[q]; }
    }
    float a0 = (float)A_h[(size_t)s0*256 + c];
    float a1 = (float)A_h[(size_t)s1*256 + c];
    float a2 = (float)A_h[(size_t)s2*256 + c];
    float a3 = (float)A_h[(size_t)s3*256 + c];
    float m0 = b0 + a0;
    float m1 = b0 + a1;
    float m2 = b0 + a2;
    float m3 = b0 + a3;
#pragma unroll
    for (int q = 0; q < 16; ++q){
      m0 = DOT2(e0.h[q], wr.h[q], m0);
      m1 = DOT2(e1.h[q], wr.h[q], m1);
      m2 = DOT2(e2.h[q], wr.h[q], m2);
      m3 = DOT2(e3.h[q], wr.h[q], m3);
    }
    s += m0; s += m1; s += m2; s += m3;
    ss = fmaf(m0, m0, ss); ss = fmaf(m1, m1, ss);
    ss = fmaf(m2, m2, ss); ss = fmaf(m3, m3, ss);
    mx = fmaxf(mx, fmaxf(fmaxf(m0, m1), fmaxf(m2, m3)));
    mn = fminf(mn, fminf(fminf(m0, m1), fminf(m2, m3)));
  }
  for (; i < cnt; ++i){
    int p = o0 + i;
    int sidx = __builtin_amdgcn_readfirstlane(esrc[p]);
    Eu e0;
    {
      const int4* p0 = (const int4*)(efh + (size_t)p*32);
#pragma unroll
      for (int q = 0; q < 4; ++q) e0.i[q] = p0[q];
    }
    float m = b0 + (float)A_h[(size_t)sidx*256 + c];
#pragma unroll
    for (int q = 0; q < 16; ++q) m = DOT2(e0.h[q], wr.h[q], m);
    s += m;
    ss = fmaf(m, m, ss);
    mx = fmaxf(mx, m);
    mn = fminf(mn, m);
  }

  float deg  = (float)cnt;
  float degc = fmaxf(deg, 1.f);
  float inv  = 1.f / degc;
  float mean = s * inv;
  float var  = fmaxf(ss * inv - mean*mean, 0.f);
  float sd   = sqrtf(var + 1e-30f);
  if (cnt == 0){ mx = 0.f; mn = 0.f; }

  int t = c >> 6, d = c & 63;
  // write agg values as bf16 hi/lo into the fragment-native X2 layout
#define PUTX(SLOT, VAL) { int kk = 64 + (SLOT)*64 + d; int jj = kk >> 3, pp = kk & 7;      \
    size_t base = (((size_t)n*4 + t)*40 + jj)*16;                                          \
    ushort hi = bf16h(VAL);                                                                \
    X2[base + pp] = hi; X2[base + 8 + pp] = bf16h((VAL) - bf16f(hi)); }
  PUTX(0, mean) PUTX(1, mx) PUTX(2, mn) PUTX(3, sd)
#undef PUTX
  if (c == 0){
    float logd = logf(deg + 1.f);
    sc[(size_t)n*2]     = logd * (1.f / DELTA_);
    sc[(size_t)n*2 + 1] = (cnt > 0) ? (DELTA_ / fmaxf(logd, 1e-12f)) : 0.f;
  }
}

// ---------- U GEMM: LDS-free MFMA, barriers only in 3-path combine epilogue ----------
// grid (N/64, 4 towers), 256 thr = 4 waves; wave w owns cols [w*48, w*48+48).
__global__ __launch_bounds__(256) void k_u(const ushort* __restrict__ X2, const ushort* __restrict__ Wpk2,
                                           const float* __restrict__ sc, const float* __restrict__ Ub,
                                           float* __restrict__ uout, int Nn){
  __shared__ float su[64][68];
  int tid = threadIdx.x;
  int t   = blockIdx.y;
  int nbase = blockIdx.x*64;
  int lane = tid & 63, wv = tid >> 6;
  int li = lane & 15, kc = lane >> 4;
  int cbase = wv*48;

  f32x4 acc[4][3];
#pragma unroll
  for (int ri = 0; ri < 4; ++ri)
#pragma unroll
    for (int ci = 0; ci < 3; ++ci) acc[ri][ci] = (f32x4)0.f;

  const ushort* wb = Wpk2 + (size_t)t*192*320;

#pragma unroll 2
  for (int kt = 0; kt < 10; ++kt){
    bf16x8 ah[4], al[4], bh[3];
#pragma unroll
    for (int ri = 0; ri < 4; ++ri){
      int row = nbase + ri*16 + li;
      if (row >= Nn) row = Nn - 1;
      const ushort* ap = X2 + (((size_t)row*4 + t)*40 + kt*4 + kc)*16;
      ah[ri] = *(const bf16x8*)(ap);
      al[ri] = *(const bf16x8*)(ap + 8);
    }
#pragma unroll
    for (int ci = 0; ci < 3; ++ci){
      int col = cbase + ci*16 + li;
      bh[ci] = *(const bf16x8*)(wb + (size_t)col*320 + kt*32 + kc*8);
    }
#pragma unroll
    for (int ci = 0; ci < 3; ++ci)
#pragma unroll
      for (int ri = 0; ri < 4; ++ri){
        acc[ri][ci] = __builtin_amdgcn_mfma_f32_16x16x32_bf16(ah[ri], bh[ci], acc[ri][ci], 0, 0, 0);
        acc[ri][ci] = __builtin_amdgcn_mfma_f32_16x16x32_bf16(al[ri], bh[ci], acc[ri][ci], 0, 0, 0);
      }
  }

  // ---- epilogue: u = y1 + amp*y2 + att*y3 (phased, col-disjoint per phase) ----
  // wave0 cols 0..47 (y1 o0..47); wave1: ci0=y1 o48..63, ci1/2=y2 o0..31;
  // wave2: ci0/1=y2 o32..63, ci2=y3 o0..15; wave3: y3 o16..63.
#define Y1_STORE(CI, OB) { _Pragma("unroll") for (int ri = 0; ri < 4; ++ri)               \
    { _Pragma("unroll") for (int r = 0; r < 4; ++r)                                        \
      su[ri*16 + kc*4 + r][(OB) + li] = acc[ri][CI][r]; } }
#define Y_ADD(CI, OB, SCOFF) { _Pragma("unroll") for (int ri = 0; ri < 4; ++ri)           \
    { _Pragma("unroll") for (int r = 0; r < 4; ++r){                                       \
      int node = ri*16 + kc*4 + r;                                                        \
      int gn = nbase + node; int gnc = (gn < Nn) ? gn : (Nn - 1);                          \
      float scl = sc[(size_t)gnc*2 + (SCOFF)];                                            \
      su[node][(OB) + li] += scl * acc[ri][CI][r]; } } }

  if (wv == 0){ Y1_STORE(0, 0)  Y1_STORE(1, 16) Y1_STORE(2, 32) }
  else if (wv == 1){ Y1_STORE(0, 48) }
  __syncthreads();
  if (wv == 1){ Y_ADD(1, 0, 0)  Y_ADD(2, 16, 0) }
  else if (wv == 2){ Y_ADD(0, 32, 0) Y_ADD(1, 48, 0) }
  __syncthreads();
  if (wv == 2){ Y_ADD(2, 0, 1) }
  else if (wv == 3){ Y_ADD(0, 16, 1) Y_ADD(1, 32, 1) Y_ADD(2, 48, 1) }
  __syncthreads();
#undef Y1_STORE
#undef Y_ADD

  for (int idx = tid; idx < 64*16; idx += 256){
    int n = idx >> 4, o4 = (idx & 15)*4;
    int gn = nbase + n;
    if (gn < Nn){
      float4 v = *(float4*)(&su[n][o4]);
      const float* ubp = Ub + t*64 + o4;
      v.x += ubp[0]; v.y += ubp[1]; v.z += ubp[2]; v.w += ubp[3];
      *(float4*)(&uout[(size_t)gn*256 + t*64 + o4]) = v;
    }
  }
}

// ---------- batchnorm stats (deterministic partials) ----------
__global__ __launch_bounds__(256) void k_bnstat(const float* __restrict__ u, float* __restrict__ part, int N){
  int c = threadIdx.x;
  int b = blockIdx.x;
  float s = 0.f, ss = 0.f;
  for (int n = b; n < N; n += gridDim.x){
    float v = u[(size_t)n*256 + c];
    s += v;
    ss = fmaf(v, v, ss);
  }
  part[(size_t)b*512 + c]       = s;
  part[(size_t)b*512 + 256 + c] = ss;
}

__global__ __launch_bounds__(256) void k_bnfin(const float* __restrict__ part, const float* __restrict__ gam,
                                               const float* __restrict__ bet, float* __restrict__ bnsc, int N){
  int c = threadIdx.x;
  float s = 0.f, ss = 0.f;
  for (int b = 0; b < BN_BLOCKS; ++b){
    s  += part[(size_t)b*512 + c];
    ss += part[(size_t)b*512 + 256 + c];
  }
  float invN = 1.f / (float)N;
  float mu  = s * invN;
  float ex2 = ss * invN;
  float var = fmaxf(ex2 - mu*mu, 0.f);
  float inv = 1.f / sqrtf(var + 1e-5f);
  float scale = gam[c] * inv;
  bnsc[c]       = scale;
  bnsc[256 + c] = bet[c] - mu*scale;
}

// ---------- X2m = bf16 hi/lo of (u*s + b), fragment-native [n][32][hi8|lo8] ----------
__global__ __launch_bounds__(256) void k_xm(const float* __restrict__ u, const float* __restrict__ bnsc,
                                            ushort* __restrict__ X2m, int N){
  for (long i = blockIdx.x*256 + threadIdx.x; i < (long)N*256; i += (long)gridDim.x*256){
    int n = (int)(i >> 8), c = (int)(i & 255);
    float v = fmaf(u[i], bnsc[c], bnsc[256 + c]);
    int j = c >> 3, pos = c & 7;
    size_t base = ((size_t)n*32 + j)*16;
    ushort hi = bf16h(v);
    X2m[base + pos]     = hi;
    X2m[base + 8 + pos] = bf16h(v - bf16f(hi));
  }
}

// ---------- mix GEMM: LDS-free MFMA + fused leaky/residual/relu ----------
// grid N/64, 256 thr = 4 waves; wave w owns cols [w*64, w*64+64).
__global__ __launch_bounds__(256) void k_mix(const ushort* __restrict__ X2m, const ushort* __restrict__ Wm2,
                                             const float* __restrict__ mixb, const float* __restrict__ nf,
                                             float* __restrict__ outp, int Nn){
  int tid = threadIdx.x;
  int nbase = blockIdx.x*64;
  int lane = tid & 63, wv = tid >> 6;
  int li = lane & 15, kc = lane >> 4;

  f32x4 acc[4][4];
#pragma unroll
  for (int ri = 0; ri < 4; ++ri)
#pragma unroll
    for (int ci = 0; ci < 4; ++ci) acc[ri][ci] = (f32x4)0.f;

#pragma unroll 2
  for (int kt = 0; kt < 8; ++kt){
    bf16x8 ah[4], al[4], bh[4];
#pragma unroll
    for (int ri = 0; ri < 4; ++ri){
      int row = nbase + ri*16 + li;
      if (row >= Nn) row = Nn - 1;
      const ushort* ap = X2m + (((size_t)row*32 + kt*4 + kc))*16;
      ah[ri] = *(const bf16x8*)(ap);
      al[ri] = *(const bf16x8*)(ap + 8);
    }
#pragma unroll
    for (int ci = 0; ci < 4; ++ci){
      int col = wv*64 + ci*16 + li;
      bh[ci] = *(const bf16x8*)(Wm2 + (size_t)col*256 + kt*32 + kc*8);
    }
#pragma unroll
    for (int ci = 0; ci < 4; ++ci)
#pragma unroll
      for (int ri = 0; ri < 4; ++ri){
        acc[ri][ci] = __builtin_amdgcn_mfma_f32_16x16x32_bf16(ah[ri], bh[ci], acc[ri][ci], 0, 0, 0);
        acc[ri][ci] = __builtin_amdgcn_mfma_f32_16x16x32_bf16(al[ri], bh[ci], acc[ri][ci], 0, 0, 0);
      }
  }

#pragma unroll
  for (int ri = 0; ri < 4; ++ri){
#pragma unroll
    for (int r = 0; r < 4; ++r){
      int node = ri*16 + kc*4 + r;
      int gn = nbase + node;
      if (gn < Nn){
#pragma unroll
        for (int ci = 0; ci < 4; ++ci){
          int col = wv*64 + ci*16 + li;
          float m = acc[ri][ci][r] + mixb[col];
          m = (m > 0.f) ? m : 0.01f*m;
          float o = m + nf[(size_t)gn*256 + col];
          outp[(size_t)gn*256 + col] = fmaxf(o, 0.f);
        }
      }
    }
  }
}

// ---------- host launcher ----------
extern "C" void kernel_launch(void* const* d_in, const int* in_sizes, int n_in,
                              void* d_out, int out_size, void* d_ws, size_t ws_size,
                              hipStream_t stream){
  const float* nf   = (const float*)d_in[0];
  const float* ef   = (const float*)d_in[1];
  const int*   srcv = (const int*)  d_in[2];
  const int*   dstv = (const int*)  d_in[3];
  const float* Mw   = (const float*)d_in[4];
  const float* Mb   = (const float*)d_in[5];
  const float* Uw   = (const float*)d_in[6];
  const float* Ub   = (const float*)d_in[7];
  const float* gam  = (const float*)d_in[8];
  const float* bet  = (const float*)d_in[9];
  const float* mixw = (const float*)d_in[10];
  const float* mixb = (const float*)d_in[11];
  int N = in_sizes[0] / 256;
  int E = in_sizes[2];
  float* out = (float*)d_out;

  char* wp = (char*)d_ws;
  auto alloc = [&](size_t bytes){
    char* p = wp;
    wp += (bytes + 1023) & ~(size_t)1023;
    return (void*)p;
  };
  int*      cnt   = (int*)     alloc((size_t)N*4);
  int*      offs  = (int*)     alloc((size_t)(N+1)*4);
  int*      cur   = (int*)     alloc((size_t)N*4);
  int*      bsum  = (int*)     alloc(256*4);
  int*      elist = (int*)     alloc((size_t)E*4);
  int*      esrc  = (int*)     alloc((size_t)E*4);
  // efh is dead after k_agg; X2m (written by k_xm) aliases it to save ws.
  size_t ealias   = (size_t)E*32*2;
  size_t malias   = (size_t)N*512*2;
  char*     shbuf = (char*)    alloc(ealias > malias ? ealias : malias);
  _Float16* efh   = (_Float16*)shbuf;
  ushort*   X2m   = (ushort*)  shbuf;
  _Float16* A_h   = (_Float16*)alloc((size_t)N*256*2);
  float*    B     = (float*)   alloc((size_t)N*256*4);
  float*    sc    = (float*)   alloc((size_t)N*2*4);
  float*    part  = (float*)   alloc((size_t)BN_BLOCKS*512*4);
  float*    bnsc  = (float*)   alloc(512*4);
  ushort*   X2    = (ushort*)  alloc((size_t)N*4*40*16*2);
  ushort*   Wpk2  = (ushort*)  alloc((size_t)4*192*320*2);
  ushort*   Wm2   = (ushort*)  alloc((size_t)256*256*2);
  _Float16* Mwefh = (_Float16*)alloc((size_t)256*32*2);

  hipMemsetAsync(cnt,  0, (size_t)N*4,  stream);
  hipMemsetAsync(cur,  0, (size_t)N*4,  stream);

  k_tU  <<<(4*192*320 + 255)/256, 256, 0, stream>>>(Uw, Wpk2);
  k_tMm <<<(256*256 + 255)/256, 256, 0, stream>>>(mixw, Wm2);
  k_tE  <<<(256*32 + 255)/256, 256, 0, stream>>>(Mw, Mwefh);
  k_hist<<<(E + 255)/256, 256, 0, stream>>>(dstv, cnt, E);
  k_ab  <<<2048, 256, 0, stream>>>(nf, Mw, Mb, A_h, B, N);
  k_xh  <<<2048, 256, 0, stream>>>(nf, X2, N);

  int NB = (N + 255)/256;
  k_scan1<<<NB, 256, 0, stream>>>(cnt, offs, bsum, N);
  k_scan2<<<1, 256, 0, stream>>>(bsum, NB);
  k_scan3<<<NB, 256, 0, stream>>>(offs, bsum, N, E);
  k_fill <<<(E + 255)/256, 256, 0, stream>>>(dstv, offs, cur, elist, E);
  k_perm <<<(E*8 + 255)/256, 256, 0, stream>>>(elist, srcv, ef, esrc, efh, E);

  k_agg<<<N, 256, 0, stream>>>(offs, esrc, efh, A_h, B, Mwefh, X2, sc, N);

  dim3 ugrid((N + 63)/64, 4);
  k_u<<<ugrid, 256, 0, stream>>>(X2, Wpk2, sc, Ub, out, N);

  k_bnstat<<<BN_BLOCKS, 256, 0, stream>>>(out, part, N);
  k_bnfin <<<1, 256, 0, stream>>>(part, gam, bet, bnsc, N);
  k_xm   <<<2048, 256, 0, stream>>>(out, bnsc, X2m, N);
  k_mix  <<<(N + 63)/64, 256, 0, stream>>>(X2m, Wm2, mixb, nf, out, N);
}